// Round 1
// baseline (2931.013 us; speedup 1.0000x reference)
//
#include <hip/hip_runtime.h>
#include <hip/hip_bf16.h>
#include <stdint.h>

#define N_ROWS 8192
#define DIM 768
#define NF 32768
#define TOPK 32
#define CHUNK 2048
#define NCHUNK 16   // NF / CHUNK
#define TCAND 16    // per-chunk kept candidates
#define RCAND 64    // refined candidates per row
#define BM 128
#define BN 128
#define BK 32
#define NSUB 16     // CHUNK / BN

typedef __attribute__((ext_vector_type(8))) short bf16x8;
typedef __attribute__((ext_vector_type(4))) float f32x4;

__device__ inline void async_ld16(const void* g, void* l) {
  __builtin_amdgcn_global_load_lds(
      (const __attribute__((address_space(1))) unsigned int*)g,
      (__attribute__((address_space(3))) unsigned int*)l, 16, 0, 0);
}

__device__ inline unsigned short f2bf(float f) {
  union { float f; unsigned u; } c; c.f = f;
  unsigned r = c.u + 0x7FFFu + ((c.u >> 16) & 1u);  // RNE
  return (unsigned short)(r >> 16);
}

// ---------------- LayerNorm: mean/std per row, x_norm -> bf16 ----------------
__global__ __launch_bounds__(256) void k_ln(const float* __restrict__ x,
                                            const float* __restrict__ pre_bias,
                                            unsigned short* __restrict__ xh,
                                            float* __restrict__ meanA,
                                            float* __restrict__ stdA) {
  int row = blockIdx.x;
  int tid = threadIdx.x;
  int lane = tid & 63, wv = tid >> 6;
  const float* xr = x + (size_t)row * DIM;
  float a0 = xr[tid], a1 = xr[tid + 256], a2 = xr[tid + 512];
  __shared__ float red[8];
  float s = a0 + a1 + a2;
  for (int off = 32; off > 0; off >>= 1) s += __shfl_down(s, off);
  if (lane == 0) red[wv] = s;
  __syncthreads();
  float mean;
  if (tid == 0) { mean = (red[0] + red[1] + red[2] + red[3]) / (float)DIM; red[4] = mean; }
  __syncthreads();
  mean = red[4];
  float d0 = a0 - mean, d1 = a1 - mean, d2 = a2 - mean;
  float ss = d0 * d0 + d1 * d1 + d2 * d2;
  for (int off = 32; off > 0; off >>= 1) ss += __shfl_down(ss, off);
  if (lane == 0) red[wv] = ss;
  __syncthreads();
  float stdv;
  if (tid == 0) {
    float var = (red[0] + red[1] + red[2] + red[3]) / (float)DIM;
    stdv = sqrtf(var + 1e-5f);
    red[5] = stdv;
    meanA[row] = mean;
    stdA[row] = stdv;
  }
  __syncthreads();
  stdv = red[5];
  float inv = 1.0f / stdv;
  unsigned short* xo = xh + (size_t)row * DIM;
  xo[tid]       = f2bf(d0 * inv - pre_bias[tid]);
  xo[tid + 256] = f2bf(d1 * inv - pre_bias[tid + 256]);
  xo[tid + 512] = f2bf(d2 * inv - pre_bias[tid + 512]);
}

// ---------------- enc_w fp32 -> bf16 ----------------
__global__ __launch_bounds__(256) void k_cv(const float* __restrict__ w,
                                            unsigned short* __restrict__ o, int n4) {
  int i = blockIdx.x * 256 + threadIdx.x;
  if (i >= n4) return;
  float4 v = ((const float4*)w)[i];
  ushort4 r;
  r.x = f2bf(v.x); r.y = f2bf(v.y); r.z = f2bf(v.z); r.w = f2bf(v.w);
  ((ushort4*)o)[i] = r;
}

// ---------------- transpose dec_w (768 x 32768) -> dect (32768 x 768) ----------------
__global__ __launch_bounds__(256) void k_tr(const float* __restrict__ dec,
                                            float* __restrict__ dect) {
  __shared__ float t[32][33];
  int tx = threadIdx.x & 31, ty = threadIdx.x >> 5;  // 32 x 8
  int fb = blockIdx.x * 32, cb = blockIdx.y * 32;
  for (int i = 0; i < 4; i++) {
    int r = ty + i * 8;
    t[r][tx] = dec[(size_t)(cb + r) * NF + fb + tx];
  }
  __syncthreads();
  for (int i = 0; i < 4; i++) {
    int r = ty + i * 8;
    dect[(size_t)(fb + r) * DIM + cb + tx] = t[tx][r];
  }
}

// ---------------- screening GEMM (bf16 MFMA) + fused per-chunk top-16 ----------------
__global__ __launch_bounds__(256) void k_gemm(const unsigned short* __restrict__ xh,
                                              const unsigned short* __restrict__ ench,
                                              const float* __restrict__ latent_bias,
                                              float* __restrict__ cvalg,
                                              int* __restrict__ cidxg) {
  __shared__ __align__(16) short sA[BM * BK];     // [128][32] bf16, 8 KB
  __shared__ __align__(16) short sB[BN * BK];     // 8 KB
  __shared__ float sC[BM * 65];                   // [128][64+1] 33.3 KB
  __shared__ float cval[BM * 17];                 // sorted ascending per row
  __shared__ unsigned short cidx[BM * 17];

  int tid = threadIdx.x;
  int lane = tid & 63;
  int w = tid >> 6;
  int wr = w >> 1, wc = w & 1;
  int chunk = blockIdx.x;
  int rowblk = blockIdx.y;

  for (int e = tid; e < BM * 16; e += 256) {
    int r = e >> 4, t = e & 15;
    cval[r * 17 + t] = -3.0e38f;
    cidx[r * 17 + t] = 0;
  }
  __syncthreads();

  const int l4 = lane & 3, ld4 = lane >> 2;            // staging lane split
  const int fr = lane & 15, fk = (lane >> 4) << 3;     // fragment lane split

  for (int sub = 0; sub < NSUB; sub++) {
    int fbase = chunk * CHUNK + sub * BN;
    f32x4 acc[4][4];
#pragma unroll
    for (int m = 0; m < 4; m++)
#pragma unroll
      for (int n = 0; n < 4; n++) {
        f32x4 z = {0.f, 0.f, 0.f, 0.f};
        acc[m][n] = z;
      }

    for (int kt = 0; kt < DIM / BK; kt++) {
      // stage A[128][32] and B[128][32]: each wave issues 2 x 1KB for each
#pragma unroll
      for (int j = 0; j < 2; j++) {
        int trow = w * 32 + j * 16 + ld4;
        size_t ga = ((size_t)(rowblk * BM + trow)) * DIM + kt * BK + l4 * 8;
        async_ld16(xh + ga, (void*)((char*)sA + w * 2048 + j * 1024));
        size_t gb = ((size_t)(fbase + trow)) * DIM + kt * BK + l4 * 8;
        async_ld16(ench + gb, (void*)((char*)sB + w * 2048 + j * 1024));
      }
      __syncthreads();
      bf16x8 af[4], bfr[4];
#pragma unroll
      for (int m = 0; m < 4; m++)
        af[m] = *(const bf16x8*)(sA + ((wr * 64 + m * 16 + fr) * BK + fk));
#pragma unroll
      for (int n = 0; n < 4; n++)
        bfr[n] = *(const bf16x8*)(sB + ((wc * 64 + n * 16 + fr) * BK + fk));
#pragma unroll
      for (int m = 0; m < 4; m++)
#pragma unroll
        for (int n = 0; n < 4; n++)
          acc[m][n] = __builtin_amdgcn_mfma_f32_16x16x32_bf16(af[m], bfr[n], acc[m][n], 0, 0, 0);
      __syncthreads();
    }

    // dump C + merge candidates, 2 stages of 64 columns
    for (int stg = 0; stg < 2; stg++) {
      if (wc == stg) {
#pragma unroll
        for (int n = 0; n < 4; n++) {
          int col = n * 16 + fr;  // 0..63 within stage
          float lb = latent_bias[fbase + stg * 64 + col];
#pragma unroll
          for (int m = 0; m < 4; m++) {
#pragma unroll
            for (int j = 0; j < 4; j++) {
              int rrow = wr * 64 + m * 16 + ((lane >> 4) << 2) + j;
              sC[rrow * 65 + col] = acc[m][n][j] + lb;
            }
          }
        }
      }
      __syncthreads();
      if (tid < BM) {
        float* cv = cval + tid * 17;
        unsigned short* cip = cidx + tid * 17;
        const float* cr = sC + tid * 65;
        int f0 = fbase + stg * 64;
        for (int c = 0; c < 64; c++) {
          float v = cr[c];
          if (v > cv[0]) {
            int p = 0;
            while (p < 15 && v > cv[p + 1]) {
              cv[p] = cv[p + 1];
              cip[p] = cip[p + 1];
              p++;
            }
            cv[p] = v;
            cip[p] = (unsigned short)(f0 + c);
          }
        }
      }
      __syncthreads();
    }
  }

  for (int e = tid; e < BM * 16; e += 256) {
    int r = e >> 4, t = e & 15;
    size_t gi = ((size_t)(rowblk * BM + r) * NCHUNK + chunk) * TCAND + t;
    cvalg[gi] = cval[r * 17 + t];
    cidxg[gi] = (int)cidx[r * 17 + t];
  }
}

// ---------------- select top-64 coarse, refine fp32, top-32 exact, decode ----------------
__global__ __launch_bounds__(256) void k_sel(const float* __restrict__ x,
                                             const float* __restrict__ pre_bias,
                                             const float* __restrict__ latent_bias,
                                             const float* __restrict__ enc,
                                             const float* __restrict__ dect,
                                             const float* __restrict__ cvalg,
                                             const int* __restrict__ cidxg,
                                             const float* __restrict__ meanA,
                                             const float* __restrict__ stdA,
                                             float* __restrict__ out) {
  __shared__ __align__(16) float xn[DIM];
  __shared__ float cv[256];
  __shared__ int ci[256];
  __shared__ int self_[RCAND];
  __shared__ float exactv[RCAND];
  __shared__ float hv[TOPK];
  __shared__ int hf[TOPK];

  int row = blockIdx.x, tid = threadIdx.x, lane = tid & 63;
  float m = meanA[row], s = stdA[row], inv = 1.0f / s;
  const float* xr = x + (size_t)row * DIM;
  for (int i = tid; i < DIM; i += 256)
    xn[i] = (xr[i] - m) * inv - pre_bias[i];
  cv[tid] = cvalg[(size_t)row * 256 + tid];
  ci[tid] = cidxg[(size_t)row * 256 + tid];
  __syncthreads();

  // top-64 coarse, wave 0 only (no barriers inside)
  if (tid < 64) {
    float r0 = cv[lane], r1 = cv[lane + 64], r2 = cv[lane + 128], r3 = cv[lane + 192];
    for (int r = 0; r < RCAND; r++) {
      float bv = r0; int bq = 0;
      if (r1 > bv) { bv = r1; bq = 1; }
      if (r2 > bv) { bv = r2; bq = 2; }
      if (r3 > bv) { bv = r3; bq = 3; }
      int bslot = bq * 64 + lane;
      for (int off = 32; off > 0; off >>= 1) {
        float ov = __shfl_down(bv, off);
        int os = __shfl_down(bslot, off);
        if (ov > bv) { bv = ov; bslot = os; }
      }
      bslot = __shfl(bslot, 0);
      if (lane == 0) self_[r] = ci[bslot];
      if ((bslot & 63) == lane) {
        int q = bslot >> 6;
        if (q == 0) r0 = -3.0e38f;
        else if (q == 1) r1 = -3.0e38f;
        else if (q == 2) r2 = -3.0e38f;
        else r3 = -3.0e38f;
      }
    }
  }
  __syncthreads();

  // exact fp32 refinement: 4 lanes per candidate
  {
    int g = tid >> 2, t4 = tid & 3;
    int f = self_[g];
    const float4* xp = (const float4*)xn;
    const float4* wp = (const float4*)(enc + (size_t)f * DIM);
    float acc = 0.f;
    for (int i = t4; i < DIM / 4; i += 4) {
      float4 a = xp[i], b = wp[i];
      acc = fmaf(a.x, b.x, acc);
      acc = fmaf(a.y, b.y, acc);
      acc = fmaf(a.z, b.z, acc);
      acc = fmaf(a.w, b.w, acc);
    }
    acc += __shfl_xor(acc, 1);
    acc += __shfl_xor(acc, 2);
    if (t4 == 0) exactv[g] = acc + latent_bias[f];
  }
  __syncthreads();

  // exact top-32 (ties -> lower feature index), wave 0
  if (tid < 64) {
    float v = exactv[lane];
    int f = self_[lane];
    for (int r = 0; r < TOPK; r++) {
      float bv = v; int bf2 = f;
      for (int off = 32; off > 0; off >>= 1) {
        float ov = __shfl_down(bv, off);
        int of = __shfl_down(bf2, off);
        if (ov > bv || (ov == bv && of < bf2)) { bv = ov; bf2 = of; }
      }
      bv = __shfl(bv, 0);
      bf2 = __shfl(bf2, 0);
      if (lane == 0) { hv[r] = bv > 0.f ? bv : 0.f; hf[r] = bf2; }
      if (f == bf2) v = -3.0e38f;
    }
  }
  __syncthreads();

  // decode + de-normalize
  float* orow = out + (size_t)row * DIM;
#pragma unroll
  for (int t = 0; t < 3; t++) {
    int c = tid + t * 256;
    float acc = pre_bias[c];
    for (int j = 0; j < TOPK; j++)
      acc = fmaf(hv[j], dect[(size_t)hf[j] * DIM + c], acc);
    orow[c] = acc * s + m;
  }
}

extern "C" void kernel_launch(void* const* d_in, const int* in_sizes, int n_in,
                              void* d_out, int out_size, void* d_ws, size_t ws_size,
                              hipStream_t stream) {
  const float* x   = (const float*)d_in[0];
  const float* pb  = (const float*)d_in[1];
  const float* lb  = (const float*)d_in[2];
  const float* enc = (const float*)d_in[3];
  const float* dec = (const float*)d_in[4];
  float* out = (float*)d_out;

  // workspace layout (bytes)
  const size_t off_xh   = 0;            // 12,582,912
  const size_t off_ench = 12582912;     // 50,331,648
  const size_t off_dect = 62914560;     // 100,663,296
  const size_t off_cval = 163577856;    // 8,388,608
  const size_t off_cidx = 171966464;    // 8,388,608
  const size_t off_mean = 180355072;    // 32,768
  const size_t off_std  = 180387840;    // 32,768
  const size_t needed   = 180420608;
  if (ws_size < needed) return;  // signals as unchanged-zero output

  char* ws = (char*)d_ws;
  unsigned short* xh   = (unsigned short*)(ws + off_xh);
  unsigned short* ench = (unsigned short*)(ws + off_ench);
  float* dect  = (float*)(ws + off_dect);
  float* cvalg = (float*)(ws + off_cval);
  int*   cidxg = (int*)(ws + off_cidx);
  float* meanA = (float*)(ws + off_mean);
  float* stdA  = (float*)(ws + off_std);

  hipLaunchKernelGGL(k_ln, dim3(N_ROWS), dim3(256), 0, stream, x, pb, xh, meanA, stdA);
  hipLaunchKernelGGL(k_cv, dim3((NF * DIM / 4 + 255) / 256), dim3(256), 0, stream,
                     enc, ench, NF * DIM / 4);
  hipLaunchKernelGGL(k_tr, dim3(NF / 32, DIM / 32), dim3(256), 0, stream, dec, dect);
  hipLaunchKernelGGL(k_gemm, dim3(NCHUNK, N_ROWS / BM), dim3(256), 0, stream,
                     xh, ench, lb, cvalg, cidxg);
  hipLaunchKernelGGL(k_sel, dim3(N_ROWS), dim3(256), 0, stream,
                     x, pb, lb, enc, dect, cvalg, cidxg, meanA, stdA, out);
}

// Round 2
// 1319.879 us; speedup vs baseline: 2.2207x; 2.2207x over previous
//
#include <hip/hip_runtime.h>
#include <hip/hip_bf16.h>
#include <stdint.h>

#define N_ROWS 8192
#define DIM 768
#define NF 32768
#define TOPK 32
#define CANDCAP 96

typedef __attribute__((ext_vector_type(8))) short bf16x8;
typedef __attribute__((ext_vector_type(8))) short short8;
typedef __attribute__((ext_vector_type(4))) float f32x4;

__device__ inline void async_ld16(const void* g, void* l) {
  __builtin_amdgcn_global_load_lds(
      (const __attribute__((address_space(1))) unsigned int*)g,
      (__attribute__((address_space(3))) unsigned int*)l, 16, 0, 0);
}

__device__ inline unsigned short f2bf(float f) {
  union { float f; unsigned u; } c; c.f = f;
  unsigned r = c.u + 0x7FFFu + ((c.u >> 16) & 1u);  // RNE
  return (unsigned short)(r >> 16);
}

__device__ inline float bf2f(unsigned short u) {
  union { unsigned u; float f; } c; c.u = ((unsigned)u) << 16;
  return c.f;
}

// ---------------- LayerNorm: mean/std per row, x_norm -> bf16 ----------------
__global__ __launch_bounds__(256) void k_ln(const float* __restrict__ x,
                                            const float* __restrict__ pre_bias,
                                            unsigned short* __restrict__ xh,
                                            float* __restrict__ meanA,
                                            float* __restrict__ stdA) {
  int row = blockIdx.x;
  int tid = threadIdx.x;
  int lane = tid & 63, wv = tid >> 6;
  const float* xr = x + (size_t)row * DIM;
  float a0 = xr[tid], a1 = xr[tid + 256], a2 = xr[tid + 512];
  __shared__ float red[8];
  float s = a0 + a1 + a2;
  for (int off = 32; off > 0; off >>= 1) s += __shfl_down(s, off);
  if (lane == 0) red[wv] = s;
  __syncthreads();
  float mean;
  if (tid == 0) { mean = (red[0] + red[1] + red[2] + red[3]) / (float)DIM; red[4] = mean; }
  __syncthreads();
  mean = red[4];
  float d0 = a0 - mean, d1 = a1 - mean, d2 = a2 - mean;
  float ss = d0 * d0 + d1 * d1 + d2 * d2;
  for (int off = 32; off > 0; off >>= 1) ss += __shfl_down(ss, off);
  if (lane == 0) red[wv] = ss;
  __syncthreads();
  float stdv;
  if (tid == 0) {
    float var = (red[0] + red[1] + red[2] + red[3]) / (float)DIM;
    stdv = sqrtf(var + 1e-5f);
    red[5] = stdv;
    meanA[row] = mean;
    stdA[row] = stdv;
  }
  __syncthreads();
  stdv = red[5];
  float inv = 1.0f / stdv;
  unsigned short* xo = xh + (size_t)row * DIM;
  xo[tid]       = f2bf(d0 * inv - pre_bias[tid]);
  xo[tid + 256] = f2bf(d1 * inv - pre_bias[tid + 256]);
  xo[tid + 512] = f2bf(d2 * inv - pre_bias[tid + 512]);
}

// ---------------- enc_w fp32 -> bf16 ----------------
__global__ __launch_bounds__(256) void k_cv(const float* __restrict__ w,
                                            unsigned short* __restrict__ o, int n4) {
  int i = blockIdx.x * 256 + threadIdx.x;
  if (i >= n4) return;
  float4 v = ((const float4*)w)[i];
  ushort4 r;
  r.x = f2bf(v.x); r.y = f2bf(v.y); r.z = f2bf(v.z); r.w = f2bf(v.w);
  ((ushort4*)o)[i] = r;
}

// -------- transpose dec_w (768 x 32768) -> dect (32768 x 768) bf16 --------
__global__ __launch_bounds__(256) void k_tr(const float* __restrict__ dec,
                                            unsigned short* __restrict__ dect) {
  __shared__ float t[32][33];
  int tx = threadIdx.x & 31, ty = threadIdx.x >> 5;  // 32 x 8
  int fb = blockIdx.x * 32, cb = blockIdx.y * 32;
  for (int i = 0; i < 4; i++) {
    int r = ty + i * 8;
    t[r][tx] = dec[(size_t)(cb + r) * NF + fb + tx];
  }
  __syncthreads();
  for (int i = 0; i < 4; i++) {
    int r = ty + i * 8;
    dect[(size_t)(fb + r) * DIM + cb + tx] = f2bf(t[tx][r]);
  }
}

// ---------------- pure 128x128 bf16 MFMA GEMM, BK=64, swizzled LDS ----------
// writes h[local_row][feature] = bf16(x_norm @ enc^T + latent_bias)
__global__ __launch_bounds__(256) void k_gemm(const unsigned short* __restrict__ xh,
                                              const unsigned short* __restrict__ ench,
                                              const float* __restrict__ latent_bias,
                                              unsigned short* __restrict__ h) {
  __shared__ __align__(16) unsigned short sA[128 * 64];  // 16 KB, swizzled
  __shared__ __align__(16) unsigned short sB[128 * 64];  // 16 KB

  int tid = threadIdx.x;
  int lane = tid & 63;
  int w = tid >> 6;
  int wr = w >> 1, wc = w & 1;
  int bx = blockIdx.x;   // N tile (feature)
  int by = blockIdx.y;   // M tile (row, chunk-local)
  const int fr = lane & 15, hi = lane >> 4;

  f32x4 acc[4][4];
#pragma unroll
  for (int m = 0; m < 4; m++)
#pragma unroll
    for (int n = 0; n < 4; n++) {
      f32x4 z = {0.f, 0.f, 0.f, 0.f};
      acc[m][n] = z;
    }

  const char* Ab = (const char*)(xh + (size_t)by * 128 * DIM);
  const char* Bb = (const char*)(ench + (size_t)bx * 128 * DIM);

  // precompute staging geometry: per-lane LDS byte L and pre-swizzled source col
  int Ls[4], scb[4], srow[4];
#pragma unroll
  for (int i = 0; i < 4; i++) {
    int L = w * 4096 + i * 1024 + lane * 16;
    Ls[i] = L;
    int r = L >> 7;
    srow[i] = r;
    scb[i] = (L & 127) ^ ((r & 7) << 4);  // inverse-swizzled source col byte
  }

  for (int kt = 0; kt < DIM / 64; kt++) {
#pragma unroll
    for (int i = 0; i < 4; i++) {
      async_ld16(Ab + (size_t)srow[i] * (DIM * 2) + kt * 128 + scb[i], (char*)sA + Ls[i]);
      async_ld16(Bb + (size_t)srow[i] * (DIM * 2) + kt * 128 + scb[i], (char*)sB + Ls[i]);
    }
    __syncthreads();  // compiler drains vmcnt here
#pragma unroll
    for (int kh = 0; kh < 2; kh++) {
      int cbb = kh * 64 + hi * 16;
      bf16x8 af[4], bfr[4];
#pragma unroll
      for (int m = 0; m < 4; m++) {
        int row = wr * 64 + m * 16 + fr;
        af[m] = *(const bf16x8*)((const char*)sA + row * 128 + (cbb ^ ((row & 7) << 4)));
      }
#pragma unroll
      for (int n = 0; n < 4; n++) {
        int row = wc * 64 + n * 16 + fr;
        bfr[n] = *(const bf16x8*)((const char*)sB + row * 128 + (cbb ^ ((row & 7) << 4)));
      }
#pragma unroll
      for (int m = 0; m < 4; m++)
#pragma unroll
        for (int n = 0; n < 4; n++)
          acc[m][n] = __builtin_amdgcn_mfma_f32_16x16x32_bf16(af[m], bfr[n], acc[m][n], 0, 0, 0);
    }
    __syncthreads();
  }

  // epilogue: add latent bias, convert bf16, store
#pragma unroll
  for (int n = 0; n < 4; n++) {
    int gcol = bx * 128 + wc * 64 + n * 16 + fr;
    float lbv = latent_bias[gcol];
#pragma unroll
    for (int m = 0; m < 4; m++) {
      int lrow = by * 128 + wr * 64 + m * 16 + hi * 4;
#pragma unroll
      for (int j = 0; j < 4; j++) {
        float v = acc[m][n][j] + lbv;
        h[(size_t)(lrow + j) * NF + gcol] = f2bf(v);
      }
    }
  }
}

// ---------------- screen: per-row top-64..96 candidates from coarse h ------
__global__ __launch_bounds__(256) void k_screen(const unsigned short* __restrict__ h,
                                                int row0,
                                                int* __restrict__ cntg,
                                                int* __restrict__ candg) {
  __shared__ int pool[1536];
  __shared__ int hist[512];
  __shared__ int hist2[128];
  __shared__ int sb_bstar, sb_chi, sb_tau, sb_cnt;
  __shared__ int cand[CANDCAP];

  int tid = threadIdx.x, lane = tid & 63;
  const unsigned short* hr = h + (size_t)blockIdx.x * NF;

  // per-thread top-6 (packed key<<15 | idx), sorted ascending c0..c5
  int c0 = -1, c1 = -1, c2 = -1, c3 = -1, c4 = -1, c5 = -1;
  for (int i = 0; i < 16; i++) {
    int base = (i * 256 + tid) * 8;
    short8 v = *(const short8*)(hr + base);
#pragma unroll
    for (int e = 0; e < 8; e++) {
      unsigned u = (unsigned short)v[e];
      unsigned key = (u & 0x8000u) ? (u ^ 0xFFFFu) : (u | 0x8000u);
      int p = (int)((key << 15) | (unsigned)(base + e));
      if (p > c0) {
        bool b1 = p > c1, b2 = p > c2, b3 = p > c3, b4 = p > c4, b5 = p > c5;
        c0 = b1 ? c1 : p;
        c1 = b1 ? (b2 ? c2 : p) : c1;
        c2 = b2 ? (b3 ? c3 : p) : c2;
        c3 = b3 ? (b4 ? c4 : p) : c3;
        c4 = b4 ? (b5 ? c5 : p) : c4;
        c5 = b5 ? p : c5;
      }
    }
  }
  hist[tid] = 0; hist[tid + 256] = 0;
  if (tid < 128) hist2[tid] = 0;
  if (tid == 0) sb_cnt = 0;
  int* pp = pool + tid * 6;
  pp[0] = c0; pp[1] = c1; pp[2] = c2; pp[3] = c3; pp[4] = c4; pp[5] = c5;
  __syncthreads();

#pragma unroll
  for (int k = 0; k < 6; k++) atomicAdd(&hist[(unsigned)pp[k] >> 22], 1);
  __syncthreads();

  // level-1: b* = max bin with suffix-count >= 64
  if (tid < 64) {
    int b = lane * 8;
    int h0 = hist[b], h1 = hist[b+1], h2 = hist[b+2], h3 = hist[b+3];
    int h4 = hist[b+4], h5 = hist[b+5], h6 = hist[b+6], h7 = hist[b+7];
    int s7 = h7, s6 = h6 + s7, s5 = h5 + s6, s4 = h4 + s5;
    int s3 = h3 + s4, s2 = h2 + s3, s1 = h1 + s2, s0 = h0 + s1;
    int tot = s0, acc = tot;
#pragma unroll
    for (int off = 1; off <= 32; off <<= 1) {
      int t = __shfl_down(acc, off);
      if (lane + off < 64) acc += t;
    }
    int excl = acc - tot;
    int best = -1, bs = 0, hb = 0;
    if (excl + s0 >= 64) { best = b + 0; bs = excl + s0; hb = h0; }
    if (excl + s1 >= 64) { best = b + 1; bs = excl + s1; hb = h1; }
    if (excl + s2 >= 64) { best = b + 2; bs = excl + s2; hb = h2; }
    if (excl + s3 >= 64) { best = b + 3; bs = excl + s3; hb = h3; }
    if (excl + s4 >= 64) { best = b + 4; bs = excl + s4; hb = h4; }
    if (excl + s5 >= 64) { best = b + 5; bs = excl + s5; hb = h5; }
    if (excl + s6 >= 64) { best = b + 6; bs = excl + s6; hb = h6; }
    if (excl + s7 >= 64) { best = b + 7; bs = excl + s7; hb = h7; }
#pragma unroll
    for (int off = 32; off > 0; off >>= 1) {
      int ob = __shfl_down(best, off), obs = __shfl_down(bs, off), ohb = __shfl_down(hb, off);
      if (lane + off < 64 && ob > best) { best = ob; bs = obs; hb = ohb; }
    }
    if (lane == 0) { sb_bstar = best; sb_chi = bs - hb; }
  }
  __syncthreads();
  int bstar = sb_bstar, chi = sb_chi;

#pragma unroll
  for (int k = 0; k < 6; k++) {
    int p = pp[k];
    if ((int)((unsigned)p >> 22) == bstar) atomicAdd(&hist2[(p >> 15) & 127], 1);
  }
  __syncthreads();

  // level-2: s* within bin b*
  if (tid < 64) {
    int g0 = hist2[lane * 2], g1 = hist2[lane * 2 + 1];
    int s1 = g1, s0 = g0 + g1;
    int tot = s0, acc = tot;
#pragma unroll
    for (int off = 1; off <= 32; off <<= 1) {
      int t = __shfl_down(acc, off);
      if (lane + off < 64) acc += t;
    }
    int excl = acc - tot;
    int best = -1;
    if (chi + excl + s0 >= 64) best = lane * 2;
    if (chi + excl + s1 >= 64) best = lane * 2 + 1;
#pragma unroll
    for (int off = 32; off > 0; off >>= 1) {
      int ob = __shfl_down(best, off);
      if (lane + off < 64 && ob > best) best = ob;
    }
    if (lane == 0) sb_tau = (bstar << 7) | best;
  }
  __syncthreads();

  int tau15 = sb_tau << 15;
#pragma unroll
  for (int k = 0; k < 6; k++) {
    int p = pp[k];
    if (p >= tau15) {
      int pos = atomicAdd(&sb_cnt, 1);
      if (pos < CANDCAP) cand[pos] = p & 32767;
    }
  }
  __syncthreads();

  int row = row0 + blockIdx.x;
  int cnt = sb_cnt < CANDCAP ? sb_cnt : CANDCAP;
  if (tid == 0) cntg[row] = cnt;
  if (tid < CANDCAP) candg[(size_t)row * CANDCAP + tid] = (tid < cnt) ? cand[tid] : 0;
}

// ------- refine candidates exact fp32, top-32, decode, de-normalize --------
__global__ __launch_bounds__(256) void k_sel(const float* __restrict__ x,
                                             const float* __restrict__ pre_bias,
                                             const float* __restrict__ latent_bias,
                                             const float* __restrict__ enc,
                                             const unsigned short* __restrict__ dect,
                                             const int* __restrict__ cntg,
                                             const int* __restrict__ candg,
                                             const float* __restrict__ meanA,
                                             const float* __restrict__ stdA,
                                             float* __restrict__ out) {
  __shared__ __align__(16) float xn[DIM];
  __shared__ float exactv[128];
  __shared__ int self_[128];
  __shared__ float hv[TOPK];
  __shared__ int hf[TOPK];

  int row = blockIdx.x, tid = threadIdx.x, lane = tid & 63;
  float m = meanA[row], s = stdA[row], inv = 1.0f / s;
  const float* xr = x + (size_t)row * DIM;
  for (int i = tid; i < DIM; i += 256)
    xn[i] = (xr[i] - m) * inv - pre_bias[i];
  int cnt = cntg[row];  // in [64, 96]
  if (tid < 128) {
    self_[tid] = (tid < cnt) ? candg[(size_t)row * CANDCAP + tid] : 0x7FFFFFF;
    exactv[tid] = -3.0e38f;
  }
  __syncthreads();

  // exact fp32 refinement: 4 lanes per candidate, 2 passes
#pragma unroll
  for (int pass = 0; pass < 2; pass++) {
    int g = pass * 64 + (tid >> 2), t4 = tid & 3;
    if (g < cnt) {
      int f = self_[g];
      const float4* xp = (const float4*)xn;
      const float4* wp = (const float4*)(enc + (size_t)f * DIM);
      float acc = 0.f;
      for (int i = t4; i < DIM / 4; i += 4) {
        float4 a = xp[i], b = wp[i];
        acc = fmaf(a.x, b.x, acc);
        acc = fmaf(a.y, b.y, acc);
        acc = fmaf(a.z, b.z, acc);
        acc = fmaf(a.w, b.w, acc);
      }
      acc += __shfl_xor(acc, 1);
      acc += __shfl_xor(acc, 2);
      if (t4 == 0) exactv[g] = acc + latent_bias[f];
    }
  }
  __syncthreads();

  // exact top-32 over up to 128 slots (ties -> lower feature index), wave 0
  if (tid < 64) {
    float v0 = exactv[lane];      int f0 = self_[lane];
    float v1 = exactv[lane + 64]; int f1 = self_[lane + 64];
    for (int r = 0; r < TOPK; r++) {
      float bv = v0; int bf = f0;
      if (v1 > bv || (v1 == bv && f1 < bf)) { bv = v1; bf = f1; }
#pragma unroll
      for (int off = 32; off > 0; off >>= 1) {
        float ov = __shfl_down(bv, off);
        int of = __shfl_down(bf, off);
        if (lane + off < 64 && (ov > bv || (ov == bv && of < bf))) { bv = ov; bf = of; }
      }
      bv = __shfl(bv, 0);
      bf = __shfl(bf, 0);
      if (lane == 0) { hv[r] = bv > 0.f ? bv : 0.f; hf[r] = bf; }
      if (f0 == bf) v0 = -3.0e38f;
      if (f1 == bf) v1 = -3.0e38f;
    }
  }
  __syncthreads();

  // decode + de-normalize
  float* orow = out + (size_t)row * DIM;
#pragma unroll
  for (int t = 0; t < 3; t++) {
    int c = tid + t * 256;
    float acc = pre_bias[c];
    for (int j = 0; j < TOPK; j++)
      acc = fmaf(hv[j], bf2f(dect[(size_t)hf[j] * DIM + c]), acc);
    orow[c] = acc * s + m;
  }
}

extern "C" void kernel_launch(void* const* d_in, const int* in_sizes, int n_in,
                              void* d_out, int out_size, void* d_ws, size_t ws_size,
                              hipStream_t stream) {
  const float* x   = (const float*)d_in[0];
  const float* pb  = (const float*)d_in[1];
  const float* lb  = (const float*)d_in[2];
  const float* enc = (const float*)d_in[3];
  const float* dec = (const float*)d_in[4];
  float* out = (float*)d_out;

  // fixed workspace layout (bytes)
  const size_t off_xh   = 0;                          // 12,582,912
  const size_t off_ench = off_xh + 12582912;          // 50,331,648
  const size_t off_dect = off_ench + 50331648;        // 50,331,648 (bf16)
  const size_t off_mean = off_dect + 50331648;        // 32,768
  const size_t off_std  = off_mean + 32768;           // 32,768
  const size_t off_cnt  = off_std + 32768;            // 32,768
  const size_t off_cand = off_cnt + 32768;            // 8192*96*4 = 3,145,728
  const size_t off_h    = off_cand + 3145728;         // chunked coarse h
  if (ws_size < off_h + (size_t)128 * NF * 2) return; // cannot run

  char* ws = (char*)d_ws;
  unsigned short* xh   = (unsigned short*)(ws + off_xh);
  unsigned short* ench = (unsigned short*)(ws + off_ench);
  unsigned short* dect = (unsigned short*)(ws + off_dect);
  float* meanA = (float*)(ws + off_mean);
  float* stdA  = (float*)(ws + off_std);
  int*   cntg  = (int*)(ws + off_cnt);
  int*   candg = (int*)(ws + off_cand);
  unsigned short* h = (unsigned short*)(ws + off_h);

  // chunk rows by available h space (multiple of 128)
  size_t avail = ws_size - off_h;
  long chunk = (long)(avail / ((size_t)NF * 2));
  chunk &= ~127L;
  if (chunk > N_ROWS) chunk = N_ROWS;
  if (chunk < 128) return;

  hipLaunchKernelGGL(k_ln, dim3(N_ROWS), dim3(256), 0, stream, x, pb, xh, meanA, stdA);
  hipLaunchKernelGGL(k_cv, dim3((NF * DIM / 4 + 255) / 256), dim3(256), 0, stream,
                     enc, ench, NF * DIM / 4);
  hipLaunchKernelGGL(k_tr, dim3(NF / 32, DIM / 32), dim3(256), 0, stream, dec, dect);

  for (int r0 = 0; r0 < N_ROWS; r0 += (int)chunk) {
    int rows = N_ROWS - r0 < (int)chunk ? N_ROWS - r0 : (int)chunk;
    hipLaunchKernelGGL(k_gemm, dim3(NF / 128, rows / 128), dim3(256), 0, stream,
                       xh + (size_t)r0 * DIM, ench, lb, h);
    hipLaunchKernelGGL(k_screen, dim3(rows), dim3(256), 0, stream, h, r0, cntg, candg);
  }

  hipLaunchKernelGGL(k_sel, dim3(N_ROWS), dim3(256), 0, stream,
                     x, pb, lb, enc, dect, cntg, candg, meanA, stdA, out);
}

// Round 6
// 1146.625 us; speedup vs baseline: 2.5562x; 1.1511x over previous
//
#include <hip/hip_runtime.h>
#include <hip/hip_bf16.h>
#include <stdint.h>

#define N_ROWS 8192
#define DIM 768
#define NF 32768
#define TOPK 32
#define CANDCAP 72
#define RTHRESH 44

typedef __attribute__((ext_vector_type(8))) short bf16x8;
typedef __attribute__((ext_vector_type(8))) short short8;
typedef __attribute__((ext_vector_type(4))) float f32x4;

__device__ inline void async_ld16(const void* g, void* l) {
  __builtin_amdgcn_global_load_lds(
      (const __attribute__((address_space(1))) unsigned int*)g,
      (__attribute__((address_space(3))) unsigned int*)l, 16, 0, 0);
}

__device__ inline unsigned short f2bf(float f) {
  union { float f; unsigned u; } c; c.f = f;
  unsigned r = c.u + 0x7FFFu + ((c.u >> 16) & 1u);  // RNE
  return (unsigned short)(r >> 16);
}

__device__ inline float bf2f(unsigned short u) {
  union { unsigned u; float f; } c; c.u = ((unsigned)u) << 16;
  return c.f;
}

// barrier that is ALSO a compiler-level memory fence (raw s_barrier is
// IntrNoMem in LLVM -> ds_reads may be hoisted across it; rule 18 family)
__device__ inline void block_barrier_fenced() {
  __builtin_amdgcn_s_barrier();
  asm volatile("" ::: "memory");          // IR-level: no memory op crosses
  __builtin_amdgcn_sched_barrier(0);      // MIR-level: no inst crosses
}

// ---------------- LayerNorm: mean/std per row, x_norm -> bf16 ----------------
__global__ __launch_bounds__(256) void k_ln(const float* __restrict__ x,
                                            const float* __restrict__ pre_bias,
                                            unsigned short* __restrict__ xh,
                                            float* __restrict__ meanA,
                                            float* __restrict__ stdA) {
  int row = blockIdx.x;
  int tid = threadIdx.x;
  int lane = tid & 63, wv = tid >> 6;
  const float* xr = x + (size_t)row * DIM;
  float a0 = xr[tid], a1 = xr[tid + 256], a2 = xr[tid + 512];
  __shared__ float red[8];
  float s = a0 + a1 + a2;
  for (int off = 32; off > 0; off >>= 1) s += __shfl_down(s, off);
  if (lane == 0) red[wv] = s;
  __syncthreads();
  float mean;
  if (tid == 0) { mean = (red[0] + red[1] + red[2] + red[3]) / (float)DIM; red[4] = mean; }
  __syncthreads();
  mean = red[4];
  float d0 = a0 - mean, d1 = a1 - mean, d2 = a2 - mean;
  float ss = d0 * d0 + d1 * d1 + d2 * d2;
  for (int off = 32; off > 0; off >>= 1) ss += __shfl_down(ss, off);
  if (lane == 0) red[wv] = ss;
  __syncthreads();
  float stdv;
  if (tid == 0) {
    float var = (red[0] + red[1] + red[2] + red[3]) / (float)DIM;
    stdv = sqrtf(var + 1e-5f);
    red[5] = stdv;
    meanA[row] = mean;
    stdA[row] = stdv;
  }
  __syncthreads();
  stdv = red[5];
  float inv = 1.0f / stdv;
  unsigned short* xo = xh + (size_t)row * DIM;
  xo[tid]       = f2bf(d0 * inv - pre_bias[tid]);
  xo[tid + 256] = f2bf(d1 * inv - pre_bias[tid + 256]);
  xo[tid + 512] = f2bf(d2 * inv - pre_bias[tid + 512]);
}

// ---------------- enc_w fp32 -> bf16 ----------------
__global__ __launch_bounds__(256) void k_cv(const float* __restrict__ w,
                                            unsigned short* __restrict__ o, int n4) {
  int i = blockIdx.x * 256 + threadIdx.x;
  if (i >= n4) return;
  float4 v = ((const float4*)w)[i];
  ushort4 r;
  r.x = f2bf(v.x); r.y = f2bf(v.y); r.z = f2bf(v.z); r.w = f2bf(v.w);
  ((ushort4*)o)[i] = r;
}

// -------- transpose dec_w (768 x 32768) -> dect (32768 x 768) bf16 --------
__global__ __launch_bounds__(256) void k_tr(const float* __restrict__ dec,
                                            unsigned short* __restrict__ dect) {
  __shared__ float t[32][33];
  int tx = threadIdx.x & 31, ty = threadIdx.x >> 5;  // 32 x 8
  int fb = blockIdx.x * 32, cb = blockIdx.y * 32;
  for (int i = 0; i < 4; i++) {
    int r = ty + i * 8;
    t[r][tx] = dec[(size_t)(cb + r) * NF + fb + tx];
  }
  __syncthreads();
  for (int i = 0; i < 4; i++) {
    int r = ty + i * 8;
    dect[(size_t)(fb + r) * DIM + cb + tx] = f2bf(t[tx][r]);
  }
}

// ---- 256x128 bf16 MFMA GEMM, BK=64, 3-buffer ring, counted vmcnt ----------
// h[local_row][feature] = bf16(x_norm @ enc^T + latent_bias)
// LDS (STATIC, 144 KB): sA 3 x 32768 B (256x64 bf16 swizzled), sB 3 x 16384 B
__global__ __launch_bounds__(512) void k_gemm(const unsigned short* __restrict__ xh,
                                              const unsigned short* __restrict__ ench,
                                              const float* __restrict__ latent_bias,
                                              unsigned short* __restrict__ h) {
  __shared__ __align__(16) char smem[147456];
  int tid = threadIdx.x;
  int lane = tid & 63;
  int w = tid >> 6;
  int wr = w >> 1, wc = w & 1;      // 4 M-waves x 2 N-waves
  int bx = blockIdx.x;              // N tile (feature / 128)
  int by = blockIdx.y;              // M tile (row / 256, chunk-local)
  const int fr = lane & 15, hi = lane >> 4;

  const char* Ab = (const char*)(xh + (size_t)by * 256 * DIM);
  const char* Bb = (const char*)(ench + (size_t)bx * 128 * DIM);

  // staging geometry: LDS dst byte L = i*8192 + tid*16 (linear); source col
  // pre-swizzled so that a swizzled ds_read sees row-major data (rule 21)
  int rA[4], cA[4];
#pragma unroll
  for (int i = 0; i < 4; i++) {
    int L = i * 8192 + tid * 16;
    int r = L >> 7;
    rA[i] = r;
    cA[i] = (L & 127) ^ ((r & 7) << 4);
  }

  f32x4 acc[4][4];
#pragma unroll
  for (int m = 0; m < 4; m++)
#pragma unroll
    for (int n = 0; n < 4; n++) {
      f32x4 z = {0.f, 0.f, 0.f, 0.f};
      acc[m][n] = z;
    }

#define STAGE(kt, b)                                                          \
  do {                                                                        \
    char* dA = smem + (b) * 32768;                                            \
    char* dB = smem + 98304 + (b) * 16384;                                    \
    _Pragma("unroll") for (int i = 0; i < 4; i++)                             \
        async_ld16(Ab + (size_t)rA[i] * (DIM * 2) + (kt) * 128 + cA[i],       \
                   dA + i * 8192 + tid * 16);                                 \
    _Pragma("unroll") for (int i = 0; i < 2; i++)                             \
        async_ld16(Bb + (size_t)rA[i] * (DIM * 2) + (kt) * 128 + cA[i],       \
                   dB + i * 8192 + tid * 16);                                 \
  } while (0)

  // prologue: tiles 0,1 in flight; wait for tile 0 (6 newest = tile 1)
  STAGE(0, 0);
  STAGE(1, 1);
  asm volatile("s_waitcnt vmcnt(6)" ::: "memory");
  block_barrier_fenced();

  for (int kt = 0; kt < 12; kt++) {
    int b = kt % 3;
    if (kt + 2 < 12) STAGE(kt + 2, (kt + 2) % 3);  // buffer freed at E_{kt-1}
    const char* pA = smem + b * 32768;
    const char* pB = smem + 98304 + b * 16384;
#pragma unroll
    for (int kh = 0; kh < 2; kh++) {
      bf16x8 af[4], bv[4];
#pragma unroll
      for (int m = 0; m < 4; m++) {
        int row = wr * 64 + m * 16 + fr;
        af[m] = *(const bf16x8*)(pA + row * 128 + ((kh * 64 + hi * 16) ^ ((row & 7) << 4)));
      }
#pragma unroll
      for (int n = 0; n < 4; n++) {
        int row = wc * 64 + n * 16 + fr;
        bv[n] = *(const bf16x8*)(pB + row * 128 + ((kh * 64 + hi * 16) ^ ((row & 7) << 4)));
      }
      __builtin_amdgcn_s_setprio(1);
#pragma unroll
      for (int m = 0; m < 4; m++)
#pragma unroll
        for (int n = 0; n < 4; n++)
          acc[m][n] = __builtin_amdgcn_mfma_f32_16x16x32_bf16(af[m], bv[n], acc[m][n], 0, 0, 0);
      __builtin_amdgcn_s_setprio(0);
    }
    // counted wait: 6 newest outstanding = tile kt+2 -> tile kt+1 resident
    if (kt < 10) asm volatile("s_waitcnt vmcnt(6)" ::: "memory");
    else if (kt == 10) asm volatile("s_waitcnt vmcnt(0)" ::: "memory");
    block_barrier_fenced();
  }
#undef STAGE

  // epilogue: add latent bias, convert bf16, store
#pragma unroll
  for (int n = 0; n < 4; n++) {
    int gcol = bx * 128 + wc * 64 + n * 16 + fr;
    float lbv = latent_bias[gcol];
#pragma unroll
    for (int m = 0; m < 4; m++) {
      int lrow = by * 256 + wr * 64 + m * 16 + hi * 4;
#pragma unroll
      for (int j = 0; j < 4; j++) {
        float v = acc[m][n][j] + lbv;
        h[(size_t)(lrow + j) * NF + gcol] = f2bf(v);
      }
    }
  }
}

// ---------------- screen: per-row top-RTHRESH.. candidates from coarse h ----
__global__ __launch_bounds__(256) void k_screen(const unsigned short* __restrict__ h,
                                                int row0,
                                                int* __restrict__ cntg,
                                                int* __restrict__ candg) {
  __shared__ int pool[1536];
  __shared__ int hist[512];
  __shared__ int hist2[128];
  __shared__ int sb_bstar, sb_chi, sb_tau, sb_cnt;
  __shared__ int cand[CANDCAP];

  int tid = threadIdx.x, lane = tid & 63;
  const unsigned short* hr = h + (size_t)blockIdx.x * NF;

  // per-thread top-6 (packed key<<15 | idx), sorted ascending c0..c5
  int c0 = -1, c1 = -1, c2 = -1, c3 = -1, c4 = -1, c5 = -1;
  for (int i = 0; i < 16; i++) {
    int base = (i * 256 + tid) * 8;
    short8 v = *(const short8*)(hr + base);
#pragma unroll
    for (int e = 0; e < 8; e++) {
      unsigned u = (unsigned short)v[e];
      unsigned key = (u & 0x8000u) ? (u ^ 0xFFFFu) : (u | 0x8000u);
      int p = (int)((key << 15) | (unsigned)(base + e));
      if (p > c0) {
        bool b1 = p > c1, b2 = p > c2, b3 = p > c3, b4 = p > c4, b5 = p > c5;
        c0 = b1 ? c1 : p;
        c1 = b1 ? (b2 ? c2 : p) : c1;
        c2 = b2 ? (b3 ? c3 : p) : c2;
        c3 = b3 ? (b4 ? c4 : p) : c3;
        c4 = b4 ? (b5 ? c5 : p) : c4;
        c5 = b5 ? p : c5;
      }
    }
  }
  hist[tid] = 0; hist[tid + 256] = 0;
  if (tid < 128) hist2[tid] = 0;
  if (tid == 0) sb_cnt = 0;
  int* pp = pool + tid * 6;
  pp[0] = c0; pp[1] = c1; pp[2] = c2; pp[3] = c3; pp[4] = c4; pp[5] = c5;
  __syncthreads();

#pragma unroll
  for (int k = 0; k < 6; k++) atomicAdd(&hist[(unsigned)pp[k] >> 22], 1);
  __syncthreads();

  // level-1: b* = max bin with suffix-count >= RTHRESH
  if (tid < 64) {
    int b = lane * 8;
    int h0 = hist[b], h1 = hist[b+1], h2 = hist[b+2], h3 = hist[b+3];
    int h4 = hist[b+4], h5 = hist[b+5], h6 = hist[b+6], h7 = hist[b+7];
    int s7 = h7, s6 = h6 + s7, s5 = h5 + s6, s4 = h4 + s5;
    int s3 = h3 + s4, s2 = h2 + s3, s1 = h1 + s2, s0 = h0 + s1;
    int tot = s0, acc = tot;
#pragma unroll
    for (int off = 1; off <= 32; off <<= 1) {
      int t = __shfl_down(acc, off);
      if (lane + off < 64) acc += t;
    }
    int excl = acc - tot;
    int best = -1, bs = 0, hb = 0;
    if (excl + s0 >= RTHRESH) { best = b + 0; bs = excl + s0; hb = h0; }
    if (excl + s1 >= RTHRESH) { best = b + 1; bs = excl + s1; hb = h1; }
    if (excl + s2 >= RTHRESH) { best = b + 2; bs = excl + s2; hb = h2; }
    if (excl + s3 >= RTHRESH) { best = b + 3; bs = excl + s3; hb = h3; }
    if (excl + s4 >= RTHRESH) { best = b + 4; bs = excl + s4; hb = h4; }
    if (excl + s5 >= RTHRESH) { best = b + 5; bs = excl + s5; hb = h5; }
    if (excl + s6 >= RTHRESH) { best = b + 6; bs = excl + s6; hb = h6; }
    if (excl + s7 >= RTHRESH) { best = b + 7; bs = excl + s7; hb = h7; }
#pragma unroll
    for (int off = 32; off > 0; off >>= 1) {
      int ob = __shfl_down(best, off), obs = __shfl_down(bs, off), ohb = __shfl_down(hb, off);
      if (lane + off < 64 && ob > best) { best = ob; bs = obs; hb = ohb; }
    }
    if (lane == 0) { sb_bstar = best; sb_chi = bs - hb; }
  }
  __syncthreads();
  int bstar = sb_bstar, chi = sb_chi;

#pragma unroll
  for (int k = 0; k < 6; k++) {
    int p = pp[k];
    if ((int)((unsigned)p >> 22) == bstar) atomicAdd(&hist2[(p >> 15) & 127], 1);
  }
  __syncthreads();

  // level-2: s* within bin b*
  if (tid < 64) {
    int g0 = hist2[lane * 2], g1 = hist2[lane * 2 + 1];
    int s1 = g1, s0 = g0 + g1;
    int tot = s0, acc = tot;
#pragma unroll
    for (int off = 1; off <= 32; off <<= 1) {
      int t = __shfl_down(acc, off);
      if (lane + off < 64) acc += t;
    }
    int excl = acc - tot;
    int best = -1;
    if (chi + excl + s0 >= RTHRESH) best = lane * 2;
    if (chi + excl + s1 >= RTHRESH) best = lane * 2 + 1;
#pragma unroll
    for (int off = 32; off > 0; off >>= 1) {
      int ob = __shfl_down(best, off);
      if (lane + off < 64 && ob > best) best = ob;
    }
    if (lane == 0) sb_tau = (bstar << 7) | best;
  }
  __syncthreads();

  int tau15 = sb_tau << 15;
#pragma unroll
  for (int k = 0; k < 6; k++) {
    int p = pp[k];
    if (p >= tau15) {
      int pos = atomicAdd(&sb_cnt, 1);
      if (pos < CANDCAP) cand[pos] = p & 32767;
    }
  }
  __syncthreads();

  int row = row0 + blockIdx.x;
  int cnt = sb_cnt < CANDCAP ? sb_cnt : CANDCAP;
  if (tid == 0) cntg[row] = cnt;
  if (tid < CANDCAP) candg[(size_t)row * CANDCAP + tid] = (tid < cnt) ? cand[tid] : 0;
}

// ------- refine candidates exact fp32, top-32, decode, de-normalize --------
__global__ __launch_bounds__(256) void k_sel(const float* __restrict__ x,
                                             const float* __restrict__ pre_bias,
                                             const float* __restrict__ latent_bias,
                                             const float* __restrict__ enc,
                                             const unsigned short* __restrict__ dect,
                                             const int* __restrict__ cntg,
                                             const int* __restrict__ candg,
                                             const float* __restrict__ meanA,
                                             const float* __restrict__ stdA,
                                             float* __restrict__ out) {
  __shared__ __align__(16) float xn[DIM];
  __shared__ float exactv[128];
  __shared__ int self_[128];
  __shared__ float hv[TOPK];
  __shared__ int hf[TOPK];

  int row = blockIdx.x, tid = threadIdx.x, lane = tid & 63;
  float m = meanA[row], s = stdA[row], inv = 1.0f / s;
  const float* xr = x + (size_t)row * DIM;
  for (int i = tid; i < DIM; i += 256)
    xn[i] = (xr[i] - m) * inv - pre_bias[i];
  int cnt = cntg[row];  // in [RTHRESH, CANDCAP]
  if (tid < 128) {
    self_[tid] = (tid < cnt) ? candg[(size_t)row * CANDCAP + tid] : 0x7FFFFFF;
    exactv[tid] = -3.0e38f;
  }
  __syncthreads();

  // exact fp32 refinement: 4 lanes per candidate, 2 passes
  // (round-1 verbatim: single accumulator, stride-4 — summation ORDER is
  //  selection-critical: reordering shifts values ~2e-6 and can flip an
  //  fp32 tie at the top-k boundary vs the np reference)
#pragma unroll
  for (int pass = 0; pass < 2; pass++) {
    int g = pass * 64 + (tid >> 2), t4 = tid & 3;
    if (g < cnt) {
      int f = self_[g];
      const float4* xp = (const float4*)xn;
      const float4* wp = (const float4*)(enc + (size_t)f * DIM);
      float acc = 0.f;
      for (int i = t4; i < DIM / 4; i += 4) {
        float4 a = xp[i], b = wp[i];
        acc = fmaf(a.x, b.x, acc);
        acc = fmaf(a.y, b.y, acc);
        acc = fmaf(a.z, b.z, acc);
        acc = fmaf(a.w, b.w, acc);
      }
      acc += __shfl_xor(acc, 1);
      acc += __shfl_xor(acc, 2);
      if (t4 == 0) exactv[g] = acc + latent_bias[f];
    }
  }
  __syncthreads();

  // exact top-32 over up to 128 slots (ties -> lower feature index), wave 0
  if (tid < 64) {
    float v0 = exactv[lane];      int f0 = self_[lane];
    float v1 = exactv[lane + 64]; int f1 = self_[lane + 64];
    for (int r = 0; r < TOPK; r++) {
      float bv = v0; int bf = f0;
      if (v1 > bv || (v1 == bv && f1 < bf)) { bv = v1; bf = f1; }
#pragma unroll
      for (int off = 32; off > 0; off >>= 1) {
        float ov = __shfl_down(bv, off);
        int of = __shfl_down(bf, off);
        if (lane + off < 64 && (ov > bv || (ov == bv && of < bf))) { bv = ov; bf = of; }
      }
      bv = __shfl(bv, 0);
      bf = __shfl(bf, 0);
      if (lane == 0) { hv[r] = bv > 0.f ? bv : 0.f; hf[r] = bf; }
      if (f0 == bf) v0 = -3.0e38f;
      if (f1 == bf) v1 = -3.0e38f;
    }
  }
  __syncthreads();

  // decode + de-normalize
  float* orow = out + (size_t)row * DIM;
#pragma unroll
  for (int t = 0; t < 3; t++) {
    int c = tid + t * 256;
    float acc = pre_bias[c];
    for (int j = 0; j < TOPK; j++)
      acc = fmaf(hv[j], bf2f(dect[(size_t)hf[j] * DIM + c]), acc);
    orow[c] = acc * s + m;
  }
}

extern "C" void kernel_launch(void* const* d_in, const int* in_sizes, int n_in,
                              void* d_out, int out_size, void* d_ws, size_t ws_size,
                              hipStream_t stream) {
  const float* x   = (const float*)d_in[0];
  const float* pb  = (const float*)d_in[1];
  const float* lb  = (const float*)d_in[2];
  const float* enc = (const float*)d_in[3];
  const float* dec = (const float*)d_in[4];
  float* out = (float*)d_out;

  // fixed workspace layout (bytes)
  const size_t off_xh   = 0;                          // 12,582,912
  const size_t off_ench = off_xh + 12582912;          // 50,331,648
  const size_t off_dect = off_ench + 50331648;        // 50,331,648 (bf16)
  const size_t off_mean = off_dect + 50331648;        // 32,768
  const size_t off_std  = off_mean + 32768;           // 32,768
  const size_t off_cnt  = off_std + 32768;            // 32,768
  const size_t off_cand = off_cnt + 32768;            // 8192*72*4 = 2,359,296
  const size_t off_h    = off_cand + 2359296;         // chunked coarse h
  if (ws_size < off_h + (size_t)256 * NF * 2) return; // cannot run

  char* ws = (char*)d_ws;
  unsigned short* xh   = (unsigned short*)(ws + off_xh);
  unsigned short* ench = (unsigned short*)(ws + off_ench);
  unsigned short* dect = (unsigned short*)(ws + off_dect);
  float* meanA = (float*)(ws + off_mean);
  float* stdA  = (float*)(ws + off_std);
  int*   cntg  = (int*)(ws + off_cnt);
  int*   candg = (int*)(ws + off_cand);
  unsigned short* h = (unsigned short*)(ws + off_h);

  // chunk rows by available h space (multiple of 256)
  size_t avail = ws_size - off_h;
  long chunk = (long)(avail / ((size_t)NF * 2));
  chunk &= ~255L;
  if (chunk > N_ROWS) chunk = N_ROWS;
  if (chunk < 256) return;

  hipLaunchKernelGGL(k_ln, dim3(N_ROWS), dim3(256), 0, stream, x, pb, xh, meanA, stdA);
  hipLaunchKernelGGL(k_cv, dim3((NF * DIM / 4 + 255) / 256), dim3(256), 0, stream,
                     enc, ench, NF * DIM / 4);
  hipLaunchKernelGGL(k_tr, dim3(NF / 32, DIM / 32), dim3(256), 0, stream, dec, dect);

  for (int r0 = 0; r0 < N_ROWS; r0 += (int)chunk) {
    int rows = N_ROWS - r0 < (int)chunk ? N_ROWS - r0 : (int)chunk;
    hipLaunchKernelGGL(k_gemm, dim3(NF / 128, rows / 256), dim3(512), 0, stream,
                       xh + (size_t)r0 * DIM, ench, lb, h);
    hipLaunchKernelGGL(k_screen, dim3(rows), dim3(256), 0, stream, h, r0, cntg, candg);
  }

  hipLaunchKernelGGL(k_sel, dim3(N_ROWS), dim3(256), 0, stream,
                     x, pb, lb, enc, dect, cntg, candg, meanA, stdA, out);
}

// Round 7
// 1146.038 us; speedup vs baseline: 2.5575x; 1.0005x over previous
//
#include <hip/hip_runtime.h>
#include <hip/hip_bf16.h>
#include <stdint.h>

#define N_ROWS 8192
#define DIM 768
#define NF 32768
#define TOPK 32
#define CANDCAP 72
#define RTHRESH 44

typedef __attribute__((ext_vector_type(8))) short bf16x8;
typedef __attribute__((ext_vector_type(8))) short short8;
typedef __attribute__((ext_vector_type(4))) float f32x4;

__device__ inline void async_ld16(const void* g, void* l) {
  __builtin_amdgcn_global_load_lds(
      (const __attribute__((address_space(1))) unsigned int*)g,
      (__attribute__((address_space(3))) unsigned int*)l, 16, 0, 0);
}

__device__ inline unsigned short f2bf(float f) {
  union { float f; unsigned u; } c; c.f = f;
  unsigned r = c.u + 0x7FFFu + ((c.u >> 16) & 1u);  // RNE
  return (unsigned short)(r >> 16);
}

__device__ inline float bf2f(unsigned short u) {
  union { unsigned u; float f; } c; c.u = ((unsigned)u) << 16;
  return c.f;
}

// barrier that is ALSO a compiler-level memory fence (raw s_barrier is
// IntrNoMem in LLVM -> ds_reads may be hoisted across it; rule 18 family)
__device__ inline void block_barrier_fenced() {
  __builtin_amdgcn_s_barrier();
  asm volatile("" ::: "memory");          // IR-level: no memory op crosses
  __builtin_amdgcn_sched_barrier(0);      // MIR-level: no inst crosses
}

// ---------------- LayerNorm: mean/std per row, x_norm -> bf16 ----------------
__global__ __launch_bounds__(256) void k_ln(const float* __restrict__ x,
                                            const float* __restrict__ pre_bias,
                                            unsigned short* __restrict__ xh,
                                            float* __restrict__ meanA,
                                            float* __restrict__ stdA) {
  int row = blockIdx.x;
  int tid = threadIdx.x;
  int lane = tid & 63, wv = tid >> 6;
  const float* xr = x + (size_t)row * DIM;
  float a0 = xr[tid], a1 = xr[tid + 256], a2 = xr[tid + 512];
  __shared__ float red[8];
  float s = a0 + a1 + a2;
  for (int off = 32; off > 0; off >>= 1) s += __shfl_down(s, off);
  if (lane == 0) red[wv] = s;
  __syncthreads();
  float mean;
  if (tid == 0) { mean = (red[0] + red[1] + red[2] + red[3]) / (float)DIM; red[4] = mean; }
  __syncthreads();
  mean = red[4];
  float d0 = a0 - mean, d1 = a1 - mean, d2 = a2 - mean;
  float ss = d0 * d0 + d1 * d1 + d2 * d2;
  for (int off = 32; off > 0; off >>= 1) ss += __shfl_down(ss, off);
  if (lane == 0) red[wv] = ss;
  __syncthreads();
  float stdv;
  if (tid == 0) {
    float var = (red[0] + red[1] + red[2] + red[3]) / (float)DIM;
    stdv = sqrtf(var + 1e-5f);
    red[5] = stdv;
    meanA[row] = mean;
    stdA[row] = stdv;
  }
  __syncthreads();
  stdv = red[5];
  float inv = 1.0f / stdv;
  unsigned short* xo = xh + (size_t)row * DIM;
  xo[tid]       = f2bf(d0 * inv - pre_bias[tid]);
  xo[tid + 256] = f2bf(d1 * inv - pre_bias[tid + 256]);
  xo[tid + 512] = f2bf(d2 * inv - pre_bias[tid + 512]);
}

// ---------------- enc_w fp32 -> bf16 ----------------
__global__ __launch_bounds__(256) void k_cv(const float* __restrict__ w,
                                            unsigned short* __restrict__ o, int n4) {
  int i = blockIdx.x * 256 + threadIdx.x;
  if (i >= n4) return;
  float4 v = ((const float4*)w)[i];
  ushort4 r;
  r.x = f2bf(v.x); r.y = f2bf(v.y); r.z = f2bf(v.z); r.w = f2bf(v.w);
  ((ushort4*)o)[i] = r;
}

// -------- transpose dec_w (768 x 32768) -> dect (32768 x 768) bf16 --------
__global__ __launch_bounds__(256) void k_tr(const float* __restrict__ dec,
                                            unsigned short* __restrict__ dect) {
  __shared__ float t[32][33];
  int tx = threadIdx.x & 31, ty = threadIdx.x >> 5;  // 32 x 8
  int fb = blockIdx.x * 32, cb = blockIdx.y * 32;
  for (int i = 0; i < 4; i++) {
    int r = ty + i * 8;
    t[r][tx] = dec[(size_t)(cb + r) * NF + fb + tx];
  }
  __syncthreads();
  for (int i = 0; i < 4; i++) {
    int r = ty + i * 8;
    dect[(size_t)(fb + r) * DIM + cb + tx] = f2bf(t[tx][r]);
  }
}

// ---- 256x128 bf16 MFMA GEMM, BK=64, 3-buffer ring, counted vmcnt,
// ---- m201-style 2-phase-per-K-step interleave (16 MFMA per phase) --------
// h[local_row][feature] = bf16(x_norm @ enc^T + latent_bias)
// LDS (STATIC, 144 KB): sA 3 x 32768 B (256x64 bf16 swizzled), sB 3 x 16384 B
__global__ __launch_bounds__(512) void k_gemm(const unsigned short* __restrict__ xh,
                                              const unsigned short* __restrict__ ench,
                                              const float* __restrict__ latent_bias,
                                              unsigned short* __restrict__ h) {
  __shared__ __align__(16) char smem[147456];
  int tid = threadIdx.x;
  int lane = tid & 63;
  int w = tid >> 6;
  int wr = w >> 1, wc = w & 1;      // 4 M-waves x 2 N-waves
  int bx = blockIdx.x;              // N tile (feature / 128)
  int by = blockIdx.y;              // M tile (row / 256, chunk-local)
  const int fr = lane & 15, hi = lane >> 4;

  const char* Ab = (const char*)(xh + (size_t)by * 256 * DIM);
  const char* Bb = (const char*)(ench + (size_t)bx * 128 * DIM);

  // staging geometry: LDS dst byte L = i*8192 + tid*16 (linear); source col
  // pre-swizzled so that a swizzled ds_read sees row-major data (rule 21)
  int rA[4], cA[4];
#pragma unroll
  for (int i = 0; i < 4; i++) {
    int L = i * 8192 + tid * 16;
    int r = L >> 7;
    rA[i] = r;
    cA[i] = (L & 127) ^ ((r & 7) << 4);
  }

  f32x4 acc[4][4];
#pragma unroll
  for (int m = 0; m < 4; m++)
#pragma unroll
    for (int n = 0; n < 4; n++) {
      f32x4 z = {0.f, 0.f, 0.f, 0.f};
      acc[m][n] = z;
    }

#define STAGE(kt, b)                                                          \
  do {                                                                        \
    char* dA = smem + (b) * 32768;                                            \
    char* dB = smem + 98304 + (b) * 16384;                                    \
    _Pragma("unroll") for (int i = 0; i < 4; i++)                             \
        async_ld16(Ab + (size_t)rA[i] * (DIM * 2) + (kt) * 128 + cA[i],       \
                   dA + i * 8192 + tid * 16);                                 \
    _Pragma("unroll") for (int i = 0; i < 2; i++)                             \
        async_ld16(Bb + (size_t)rA[i] * (DIM * 2) + (kt) * 128 + cA[i],       \
                   dB + i * 8192 + tid * 16);                                 \
  } while (0)

  // prologue: tiles 0,1 in flight; wait for tile 0 (6 newest = tile 1)
  STAGE(0, 0);
  STAGE(1, 1);
  asm volatile("s_waitcnt vmcnt(6)" ::: "memory");
  block_barrier_fenced();

  for (int kt = 0; kt < 12; kt++) {
    int b = kt % 3;
    const char* pA = smem + b * 32768;
    const char* pB = smem + 98304 + b * 16384;
    int sb = (kt + 2) % 3;
    char* dA = smem + sb * 32768;
    char* dB = smem + 98304 + sb * 16384;
    bool doStage = (kt + 2 < 12);

#pragma unroll
    for (int kh = 0; kh < 2; kh++) {
      // --- phase: ds-read register subtile ---
      bf16x8 af[4], bv[4];
      int cbb = kh * 64 + hi * 16;
#pragma unroll
      for (int m = 0; m < 4; m++) {
        int row = wr * 64 + m * 16 + fr;
        af[m] = *(const bf16x8*)(pA + row * 128 + (cbb ^ ((row & 7) << 4)));
      }
#pragma unroll
      for (int n = 0; n < 4; n++) {
        int row = wc * 64 + n * 16 + fr;
        bv[n] = *(const bf16x8*)(pB + row * 128 + (cbb ^ ((row & 7) << 4)));
      }
      // --- phase: stage half of tile kt+2 (3 x global_load_lds) ---
      if (doStage) {
        int i0 = kh * 2;
        async_ld16(Ab + (size_t)rA[i0] * (DIM * 2) + (kt + 2) * 128 + cA[i0],
                   dA + i0 * 8192 + tid * 16);
        async_ld16(Ab + (size_t)rA[i0 + 1] * (DIM * 2) + (kt + 2) * 128 + cA[i0 + 1],
                   dA + (i0 + 1) * 8192 + tid * 16);
        async_ld16(Bb + (size_t)rA[kh] * (DIM * 2) + (kt + 2) * 128 + cA[kh],
                   dB + kh * 8192 + tid * 16);
      }
      // --- barrier: all waves' ds_reads issued before MFMA wavefront ---
      asm volatile("" ::: "memory");    // pin ds_read/gload issues above
      __builtin_amdgcn_s_barrier();
      __builtin_amdgcn_s_setprio(1);
#pragma unroll
      for (int m = 0; m < 4; m++)
#pragma unroll
        for (int n = 0; n < 4; n++)
          acc[m][n] = __builtin_amdgcn_mfma_f32_16x16x32_bf16(af[m], bv[n], acc[m][n], 0, 0, 0);
      __builtin_amdgcn_s_setprio(0);
      // counted wait once per K-step (end of phase 2): 6 newest outstanding
      // = tile kt+2 -> tile kt+1 provably resident; no drain in main loop
      if (kh == 1) {
        if (kt < 10) asm volatile("s_waitcnt vmcnt(6)" ::: "memory");
        else if (kt == 10) asm volatile("s_waitcnt vmcnt(0)" ::: "memory");
      }
      block_barrier_fenced();
    }
  }
#undef STAGE

  // epilogue: add latent bias, convert bf16, store
#pragma unroll
  for (int n = 0; n < 4; n++) {
    int gcol = bx * 128 + wc * 64 + n * 16 + fr;
    float lbv = latent_bias[gcol];
#pragma unroll
    for (int m = 0; m < 4; m++) {
      int lrow = by * 256 + wr * 64 + m * 16 + hi * 4;
#pragma unroll
      for (int j = 0; j < 4; j++) {
        float v = acc[m][n][j] + lbv;
        h[(size_t)(lrow + j) * NF + gcol] = f2bf(v);
      }
    }
  }
}

// ---------------- screen: per-row top-RTHRESH.. candidates from coarse h ----
__global__ __launch_bounds__(256) void k_screen(const unsigned short* __restrict__ h,
                                                int row0,
                                                int* __restrict__ cntg,
                                                int* __restrict__ candg) {
  __shared__ int pool[1536];
  __shared__ int hist[512];
  __shared__ int hist2[128];
  __shared__ int sb_bstar, sb_chi, sb_tau, sb_cnt;
  __shared__ int cand[CANDCAP];

  int tid = threadIdx.x, lane = tid & 63;
  const unsigned short* hr = h + (size_t)blockIdx.x * NF;

  // per-thread top-6 (packed key<<15 | idx), sorted ascending c0..c5
  int c0 = -1, c1 = -1, c2 = -1, c3 = -1, c4 = -1, c5 = -1;
  for (int i = 0; i < 16; i++) {
    int base = (i * 256 + tid) * 8;
    short8 v = *(const short8*)(hr + base);
#pragma unroll
    for (int e = 0; e < 8; e++) {
      unsigned u = (unsigned short)v[e];
      unsigned key = (u & 0x8000u) ? (u ^ 0xFFFFu) : (u | 0x8000u);
      int p = (int)((key << 15) | (unsigned)(base + e));
      if (p > c0) {
        bool b1 = p > c1, b2 = p > c2, b3 = p > c3, b4 = p > c4, b5 = p > c5;
        c0 = b1 ? c1 : p;
        c1 = b1 ? (b2 ? c2 : p) : c1;
        c2 = b2 ? (b3 ? c3 : p) : c2;
        c3 = b3 ? (b4 ? c4 : p) : c3;
        c4 = b4 ? (b5 ? c5 : p) : c4;
        c5 = b5 ? p : c5;
      }
    }
  }
  hist[tid] = 0; hist[tid + 256] = 0;
  if (tid < 128) hist2[tid] = 0;
  if (tid == 0) sb_cnt = 0;
  int* pp = pool + tid * 6;
  pp[0] = c0; pp[1] = c1; pp[2] = c2; pp[3] = c3; pp[4] = c4; pp[5] = c5;
  __syncthreads();

#pragma unroll
  for (int k = 0; k < 6; k++) atomicAdd(&hist[(unsigned)pp[k] >> 22], 1);
  __syncthreads();

  // level-1: b* = max bin with suffix-count >= RTHRESH
  if (tid < 64) {
    int b = lane * 8;
    int h0 = hist[b], h1 = hist[b+1], h2 = hist[b+2], h3 = hist[b+3];
    int h4 = hist[b+4], h5 = hist[b+5], h6 = hist[b+6], h7 = hist[b+7];
    int s7 = h7, s6 = h6 + s7, s5 = h5 + s6, s4 = h4 + s5;
    int s3 = h3 + s4, s2 = h2 + s3, s1 = h1 + s2, s0 = h0 + s1;
    int tot = s0, acc = tot;
#pragma unroll
    for (int off = 1; off <= 32; off <<= 1) {
      int t = __shfl_down(acc, off);
      if (lane + off < 64) acc += t;
    }
    int excl = acc - tot;
    int best = -1, bs = 0, hb = 0;
    if (excl + s0 >= RTHRESH) { best = b + 0; bs = excl + s0; hb = h0; }
    if (excl + s1 >= RTHRESH) { best = b + 1; bs = excl + s1; hb = h1; }
    if (excl + s2 >= RTHRESH) { best = b + 2; bs = excl + s2; hb = h2; }
    if (excl + s3 >= RTHRESH) { best = b + 3; bs = excl + s3; hb = h3; }
    if (excl + s4 >= RTHRESH) { best = b + 4; bs = excl + s4; hb = h4; }
    if (excl + s5 >= RTHRESH) { best = b + 5; bs = excl + s5; hb = h5; }
    if (excl + s6 >= RTHRESH) { best = b + 6; bs = excl + s6; hb = h6; }
    if (excl + s7 >= RTHRESH) { best = b + 7; bs = excl + s7; hb = h7; }
#pragma unroll
    for (int off = 32; off > 0; off >>= 1) {
      int ob = __shfl_down(best, off), obs = __shfl_down(bs, off), ohb = __shfl_down(hb, off);
      if (lane + off < 64 && ob > best) { best = ob; bs = obs; hb = ohb; }
    }
    if (lane == 0) { sb_bstar = best; sb_chi = bs - hb; }
  }
  __syncthreads();
  int bstar = sb_bstar, chi = sb_chi;

#pragma unroll
  for (int k = 0; k < 6; k++) {
    int p = pp[k];
    if ((int)((unsigned)p >> 22) == bstar) atomicAdd(&hist2[(p >> 15) & 127], 1);
  }
  __syncthreads();

  // level-2: s* within bin b*
  if (tid < 64) {
    int g0 = hist2[lane * 2], g1 = hist2[lane * 2 + 1];
    int s1 = g1, s0 = g0 + g1;
    int tot = s0, acc = tot;
#pragma unroll
    for (int off = 1; off <= 32; off <<= 1) {
      int t = __shfl_down(acc, off);
      if (lane + off < 64) acc += t;
    }
    int excl = acc - tot;
    int best = -1;
    if (chi + excl + s0 >= RTHRESH) best = lane * 2;
    if (chi + excl + s1 >= RTHRESH) best = lane * 2 + 1;
#pragma unroll
    for (int off = 32; off > 0; off >>= 1) {
      int ob = __shfl_down(best, off);
      if (lane + off < 64 && ob > best) best = ob;
    }
    if (lane == 0) sb_tau = (bstar << 7) | best;
  }
  __syncthreads();

  int tau15 = sb_tau << 15;
#pragma unroll
  for (int k = 0; k < 6; k++) {
    int p = pp[k];
    if (p >= tau15) {
      int pos = atomicAdd(&sb_cnt, 1);
      if (pos < CANDCAP) cand[pos] = p & 32767;
    }
  }
  __syncthreads();

  int row = row0 + blockIdx.x;
  int cnt = sb_cnt < CANDCAP ? sb_cnt : CANDCAP;
  if (tid == 0) cntg[row] = cnt;
  if (tid < CANDCAP) candg[(size_t)row * CANDCAP + tid] = (tid < cnt) ? cand[tid] : 0;
}

// ------- refine candidates exact fp32, top-32, decode, de-normalize --------
__global__ __launch_bounds__(256) void k_sel(const float* __restrict__ x,
                                             const float* __restrict__ pre_bias,
                                             const float* __restrict__ latent_bias,
                                             const float* __restrict__ enc,
                                             const unsigned short* __restrict__ dect,
                                             const int* __restrict__ cntg,
                                             const int* __restrict__ candg,
                                             const float* __restrict__ meanA,
                                             const float* __restrict__ stdA,
                                             float* __restrict__ out) {
  __shared__ __align__(16) float xn[DIM];
  __shared__ float exactv[128];
  __shared__ int self_[128];
  __shared__ float hv[TOPK];
  __shared__ int hf[TOPK];

  int row = blockIdx.x, tid = threadIdx.x, lane = tid & 63;
  float m = meanA[row], s = stdA[row], inv = 1.0f / s;
  const float* xr = x + (size_t)row * DIM;
  for (int i = tid; i < DIM; i += 256)
    xn[i] = (xr[i] - m) * inv - pre_bias[i];
  int cnt = cntg[row];  // in [RTHRESH, CANDCAP]
  if (tid < 128) {
    self_[tid] = (tid < cnt) ? candg[(size_t)row * CANDCAP + tid] : 0x7FFFFFF;
    exactv[tid] = -3.0e38f;
  }
  __syncthreads();

  // exact fp32 refinement: 4 lanes per candidate, 2 passes
  // (round-1 verbatim: single accumulator, stride-4 — summation ORDER is
  //  selection-critical: reordering shifts values ~2e-6 and can flip an
  //  fp32 tie at the top-k boundary vs the np reference)
#pragma unroll
  for (int pass = 0; pass < 2; pass++) {
    int g = pass * 64 + (tid >> 2), t4 = tid & 3;
    if (g < cnt) {
      int f = self_[g];
      const float4* xp = (const float4*)xn;
      const float4* wp = (const float4*)(enc + (size_t)f * DIM);
      float acc = 0.f;
      for (int i = t4; i < DIM / 4; i += 4) {
        float4 a = xp[i], b = wp[i];
        acc = fmaf(a.x, b.x, acc);
        acc = fmaf(a.y, b.y, acc);
        acc = fmaf(a.z, b.z, acc);
        acc = fmaf(a.w, b.w, acc);
      }
      acc += __shfl_xor(acc, 1);
      acc += __shfl_xor(acc, 2);
      if (t4 == 0) exactv[g] = acc + latent_bias[f];
    }
  }
  __syncthreads();

  // exact top-32 over up to 128 slots (ties -> lower feature index), wave 0
  if (tid < 64) {
    float v0 = exactv[lane];      int f0 = self_[lane];
    float v1 = exactv[lane + 64]; int f1 = self_[lane + 64];
    for (int r = 0; r < TOPK; r++) {
      float bv = v0; int bf = f0;
      if (v1 > bv || (v1 == bv && f1 < bf)) { bv = v1; bf = f1; }
#pragma unroll
      for (int off = 32; off > 0; off >>= 1) {
        float ov = __shfl_down(bv, off);
        int of = __shfl_down(bf, off);
        if (lane + off < 64 && (ov > bv || (ov == bv && of < bf))) { bv = ov; bf = of; }
      }
      bv = __shfl(bv, 0);
      bf = __shfl(bf, 0);
      if (lane == 0) { hv[r] = bv > 0.f ? bv : 0.f; hf[r] = bf; }
      if (f0 == bf) v0 = -3.0e38f;
      if (f1 == bf) v1 = -3.0e38f;
    }
  }
  __syncthreads();

  // decode + de-normalize
  float* orow = out + (size_t)row * DIM;
#pragma unroll
  for (int t = 0; t < 3; t++) {
    int c = tid + t * 256;
    float acc = pre_bias[c];
    for (int j = 0; j < TOPK; j++)
      acc = fmaf(hv[j], bf2f(dect[(size_t)hf[j] * DIM + c]), acc);
    orow[c] = acc * s + m;
  }
}

extern "C" void kernel_launch(void* const* d_in, const int* in_sizes, int n_in,
                              void* d_out, int out_size, void* d_ws, size_t ws_size,
                              hipStream_t stream) {
  const float* x   = (const float*)d_in[0];
  const float* pb  = (const float*)d_in[1];
  const float* lb  = (const float*)d_in[2];
  const float* enc = (const float*)d_in[3];
  const float* dec = (const float*)d_in[4];
  float* out = (float*)d_out;

  // fixed workspace layout (bytes)
  const size_t off_xh   = 0;                          // 12,582,912
  const size_t off_ench = off_xh + 12582912;          // 50,331,648
  const size_t off_dect = off_ench + 50331648;        // 50,331,648 (bf16)
  const size_t off_mean = off_dect + 50331648;        // 32,768
  const size_t off_std  = off_mean + 32768;           // 32,768
  const size_t off_cnt  = off_std + 32768;            // 32,768
  const size_t off_cand = off_cnt + 32768;            // 8192*72*4 = 2,359,296
  const size_t off_h    = off_cand + 2359296;         // chunked coarse h
  if (ws_size < off_h + (size_t)256 * NF * 2) return; // cannot run

  char* ws = (char*)d_ws;
  unsigned short* xh   = (unsigned short*)(ws + off_xh);
  unsigned short* ench = (unsigned short*)(ws + off_ench);
  unsigned short* dect = (unsigned short*)(ws + off_dect);
  float* meanA = (float*)(ws + off_mean);
  float* stdA  = (float*)(ws + off_std);
  int*   cntg  = (int*)(ws + off_cnt);
  int*   candg = (int*)(ws + off_cand);
  unsigned short* h = (unsigned short*)(ws + off_h);

  // chunk rows by available h space (multiple of 256)
  size_t avail = ws_size - off_h;
  long chunk = (long)(avail / ((size_t)NF * 2));
  chunk &= ~255L;
  if (chunk > N_ROWS) chunk = N_ROWS;
  if (chunk < 256) return;

  hipLaunchKernelGGL(k_ln, dim3(N_ROWS), dim3(256), 0, stream, x, pb, xh, meanA, stdA);
  hipLaunchKernelGGL(k_cv, dim3((NF * DIM / 4 + 255) / 256), dim3(256), 0, stream,
                     enc, ench, NF * DIM / 4);
  hipLaunchKernelGGL(k_tr, dim3(NF / 32, DIM / 32), dim3(256), 0, stream, dec, dect);

  for (int r0 = 0; r0 < N_ROWS; r0 += (int)chunk) {
    int rows = N_ROWS - r0 < (int)chunk ? N_ROWS - r0 : (int)chunk;
    hipLaunchKernelGGL(k_gemm, dim3(NF / 128, rows / 256), dim3(512), 0, stream,
                       xh + (size_t)r0 * DIM, ench, lb, h);
    hipLaunchKernelGGL(k_screen, dim3(rows), dim3(256), 0, stream, h, r0, cntg, candg);
  }

  hipLaunchKernelGGL(k_sel, dim3(N_ROWS), dim3(256), 0, stream,
                     x, pb, lb, enc, dect, cntg, candg, meanA, stdA, out);
}

// Round 8
// 1101.327 us; speedup vs baseline: 2.6613x; 1.0406x over previous
//
#include <hip/hip_runtime.h>
#include <hip/hip_bf16.h>
#include <stdint.h>

#define N_ROWS 8192
#define DIM 768
#define NF 32768
#define TOPK 32
#define CANDCAP 72
#define RTHRESH 44

typedef __attribute__((ext_vector_type(8))) short bf16x8;
typedef __attribute__((ext_vector_type(8))) short short8;
typedef __attribute__((ext_vector_type(4))) float f32x4;

__device__ inline void async_ld16(const void* g, void* l) {
  __builtin_amdgcn_global_load_lds(
      (const __attribute__((address_space(1))) unsigned int*)g,
      (__attribute__((address_space(3))) unsigned int*)l, 16, 0, 0);
}

__device__ inline unsigned short f2bf(float f) {
  union { float f; unsigned u; } c; c.f = f;
  unsigned r = c.u + 0x7FFFu + ((c.u >> 16) & 1u);  // RNE
  return (unsigned short)(r >> 16);
}

__device__ inline float bf2f(unsigned short u) {
  union { unsigned u; float f; } c; c.u = ((unsigned)u) << 16;
  return c.f;
}

// barrier that is ALSO a compiler-level memory fence
__device__ inline void block_barrier_fenced() {
  __builtin_amdgcn_s_barrier();
  asm volatile("" ::: "memory");
  __builtin_amdgcn_sched_barrier(0);
}

// ---------------- LayerNorm: mean/std per row, x_norm -> bf16 ----------------
__global__ __launch_bounds__(256) void k_ln(const float* __restrict__ x,
                                            const float* __restrict__ pre_bias,
                                            unsigned short* __restrict__ xh,
                                            float* __restrict__ meanA,
                                            float* __restrict__ stdA) {
  int row = blockIdx.x;
  int tid = threadIdx.x;
  int lane = tid & 63, wv = tid >> 6;
  const float* xr = x + (size_t)row * DIM;
  float a0 = xr[tid], a1 = xr[tid + 256], a2 = xr[tid + 512];
  __shared__ float red[8];
  float s = a0 + a1 + a2;
  for (int off = 32; off > 0; off >>= 1) s += __shfl_down(s, off);
  if (lane == 0) red[wv] = s;
  __syncthreads();
  float mean;
  if (tid == 0) { mean = (red[0] + red[1] + red[2] + red[3]) / (float)DIM; red[4] = mean; }
  __syncthreads();
  mean = red[4];
  float d0 = a0 - mean, d1 = a1 - mean, d2 = a2 - mean;
  float ss = d0 * d0 + d1 * d1 + d2 * d2;
  for (int off = 32; off > 0; off >>= 1) ss += __shfl_down(ss, off);
  if (lane == 0) red[wv] = ss;
  __syncthreads();
  float stdv;
  if (tid == 0) {
    float var = (red[0] + red[1] + red[2] + red[3]) / (float)DIM;
    stdv = sqrtf(var + 1e-5f);
    red[5] = stdv;
    meanA[row] = mean;
    stdA[row] = stdv;
  }
  __syncthreads();
  stdv = red[5];
  float inv = 1.0f / stdv;
  unsigned short* xo = xh + (size_t)row * DIM;
  xo[tid]       = f2bf(d0 * inv - pre_bias[tid]);
  xo[tid + 256] = f2bf(d1 * inv - pre_bias[tid + 256]);
  xo[tid + 512] = f2bf(d2 * inv - pre_bias[tid + 512]);
}

// ---------------- enc_w fp32 -> bf16 ----------------
__global__ __launch_bounds__(256) void k_cv(const float* __restrict__ w,
                                            unsigned short* __restrict__ o, int n4) {
  int i = blockIdx.x * 256 + threadIdx.x;
  if (i >= n4) return;
  float4 v = ((const float4*)w)[i];
  ushort4 r;
  r.x = f2bf(v.x); r.y = f2bf(v.y); r.z = f2bf(v.z); r.w = f2bf(v.w);
  ((ushort4*)o)[i] = r;
}

// -------- transpose dec_w (768 x 32768) -> dect (32768 x 768) bf16 --------
__global__ __launch_bounds__(256) void k_tr(const float* __restrict__ dec,
                                            unsigned short* __restrict__ dect) {
  __shared__ float t[32][33];
  int tx = threadIdx.x & 31, ty = threadIdx.x >> 5;  // 32 x 8
  int fb = blockIdx.x * 32, cb = blockIdx.y * 32;
  for (int i = 0; i < 4; i++) {
    int r = ty + i * 8;
    t[r][tx] = dec[(size_t)(cb + r) * NF + fb + tx];
  }
  __syncthreads();
  for (int i = 0; i < 4; i++) {
    int r = ty + i * 8;
    dect[(size_t)(fb + r) * DIM + cb + tx] = f2bf(t[tx][r]);
  }
}

// ---- 256x128 bf16 MFMA GEMM, BK=64, 3-buffer ring, counted vmcnt, ----------
// ---- fused per-(row, 128-col-slice) top-6 candidate epilogue (h deleted) ---
// cand6[row][bx][0..5] = packed (orderable_fp32_key & 0xFFFFFF00) | col7
// LDS (STATIC, 144 KB): K-loop ring; reused post-loop as sC[256][129] + m6
__global__ __launch_bounds__(512) void k_gemm(const unsigned short* __restrict__ xh,
                                              const unsigned short* __restrict__ ench,
                                              const float* __restrict__ latent_bias,
                                              unsigned* __restrict__ cand6) {
  __shared__ __align__(16) char smem[147456];
  int tid = threadIdx.x;
  int lane = tid & 63;
  int w = tid >> 6;
  int wr = w >> 1, wc = w & 1;      // 4 M-waves x 2 N-waves
  int bx = blockIdx.x;              // N tile (feature / 128)
  int by = blockIdx.y;              // M tile (row / 256)
  const int fr = lane & 15, hi = lane >> 4;

  const char* Ab = (const char*)(xh + (size_t)by * 256 * DIM);
  const char* Bb = (const char*)(ench + (size_t)bx * 128 * DIM);

  int rA[4], cA[4];
#pragma unroll
  for (int i = 0; i < 4; i++) {
    int L = i * 8192 + tid * 16;
    int r = L >> 7;
    rA[i] = r;
    cA[i] = (L & 127) ^ ((r & 7) << 4);
  }

  f32x4 acc[4][4];
#pragma unroll
  for (int m = 0; m < 4; m++)
#pragma unroll
    for (int n = 0; n < 4; n++) {
      f32x4 z = {0.f, 0.f, 0.f, 0.f};
      acc[m][n] = z;
    }

#define STAGE(kt, b)                                                          \
  do {                                                                        \
    char* dA = smem + (b) * 32768;                                            \
    char* dB = smem + 98304 + (b) * 16384;                                    \
    _Pragma("unroll") for (int i = 0; i < 4; i++)                             \
        async_ld16(Ab + (size_t)rA[i] * (DIM * 2) + (kt) * 128 + cA[i],       \
                   dA + i * 8192 + tid * 16);                                 \
    _Pragma("unroll") for (int i = 0; i < 2; i++)                             \
        async_ld16(Bb + (size_t)rA[i] * (DIM * 2) + (kt) * 128 + cA[i],       \
                   dB + i * 8192 + tid * 16);                                 \
  } while (0)

  STAGE(0, 0);
  STAGE(1, 1);
  asm volatile("s_waitcnt vmcnt(6)" ::: "memory");
  block_barrier_fenced();

  for (int kt = 0; kt < 12; kt++) {
    int b = kt % 3;
    const char* pA = smem + b * 32768;
    const char* pB = smem + 98304 + b * 16384;
    int sb = (kt + 2) % 3;
    char* dA = smem + sb * 32768;
    char* dB = smem + 98304 + sb * 16384;
    bool doStage = (kt + 2 < 12);

#pragma unroll
    for (int kh = 0; kh < 2; kh++) {
      bf16x8 af[4], bv[4];
      int cbb = kh * 64 + hi * 16;
#pragma unroll
      for (int m = 0; m < 4; m++) {
        int row = wr * 64 + m * 16 + fr;
        af[m] = *(const bf16x8*)(pA + row * 128 + (cbb ^ ((row & 7) << 4)));
      }
#pragma unroll
      for (int n = 0; n < 4; n++) {
        int row = wc * 64 + n * 16 + fr;
        bv[n] = *(const bf16x8*)(pB + row * 128 + (cbb ^ ((row & 7) << 4)));
      }
      if (doStage) {
        int i0 = kh * 2;
        async_ld16(Ab + (size_t)rA[i0] * (DIM * 2) + (kt + 2) * 128 + cA[i0],
                   dA + i0 * 8192 + tid * 16);
        async_ld16(Ab + (size_t)rA[i0 + 1] * (DIM * 2) + (kt + 2) * 128 + cA[i0 + 1],
                   dA + (i0 + 1) * 8192 + tid * 16);
        async_ld16(Bb + (size_t)rA[kh] * (DIM * 2) + (kt + 2) * 128 + cA[kh],
                   dB + kh * 8192 + tid * 16);
      }
      asm volatile("" ::: "memory");
      __builtin_amdgcn_s_barrier();
      __builtin_amdgcn_s_setprio(1);
#pragma unroll
      for (int m = 0; m < 4; m++)
#pragma unroll
        for (int n = 0; n < 4; n++)
          acc[m][n] = __builtin_amdgcn_mfma_f32_16x16x32_bf16(af[m], bv[n], acc[m][n], 0, 0, 0);
      __builtin_amdgcn_s_setprio(0);
      if (kh == 1) {
        if (kt < 10) asm volatile("s_waitcnt vmcnt(6)" ::: "memory");
        else if (kt == 10) asm volatile("s_waitcnt vmcnt(0)" ::: "memory");
      }
      block_barrier_fenced();
    }
  }
#undef STAGE

  // ---- fused epilogue: bias, dump to LDS, per-row top-6 of this 128-slice --
  float* sC = (float*)smem;                 // [256][129] = 132096 B
  int* m6 = (int*)(smem + 132096);          // [512][6]   =  12288 B
#pragma unroll
  for (int n = 0; n < 4; n++) {
    int lcol = wc * 64 + n * 16 + fr;
    float lbv = latent_bias[bx * 128 + lcol];
#pragma unroll
    for (int m = 0; m < 4; m++) {
      int lrow = wr * 64 + m * 16 + hi * 4;
#pragma unroll
      for (int j = 0; j < 4; j++)
        sC[(lrow + j) * 129 + lcol] = acc[m][n][j] + lbv;
    }
  }
  __syncthreads();
  {
    // 2 threads per row scan 64 cols each -> register top-6 (sorted asc c0..c5)
    int r = tid >> 1, half = tid & 1;
    const float* cr = sC + r * 129 + half * 64;
    unsigned c0 = 0, c1 = 0, c2 = 0, c3 = 0, c4 = 0, c5 = 0;
    for (int c = 0; c < 64; c++) {
      union { float f; unsigned u; } cv; cv.f = cr[c];
      unsigned key = ((int)cv.u < 0) ? ~cv.u : (cv.u | 0x80000000u);
      unsigned p = (key & 0xFFFFFF00u) | (unsigned)(half * 64 + c);
      if (p > c0) {
        bool b1 = p > c1, b2 = p > c2, b3 = p > c3, b4 = p > c4, b5 = p > c5;
        c0 = b1 ? c1 : p;
        c1 = b1 ? (b2 ? c2 : p) : c1;
        c2 = b2 ? (b3 ? c3 : p) : c2;
        c3 = b3 ? (b4 ? c4 : p) : c3;
        c4 = b4 ? (b5 ? c5 : p) : c4;
        c5 = b5 ? p : c5;
      }
    }
    int* mp = m6 + tid * 6;
    mp[0] = (int)c0; mp[1] = (int)c1; mp[2] = (int)c2;
    mp[3] = (int)c3; mp[4] = (int)c4; mp[5] = (int)c5;
  }
  __syncthreads();
  if (tid < 256) {
    // merge the two halves' sorted-asc top-6 -> row top-6, write packed
    const int* A = m6 + (2 * tid) * 6;
    const int* B = m6 + (2 * tid + 1) * 6;
    unsigned* dst = cand6 + ((size_t)(by * 256 + tid) * 256 + bx) * 6;
    int ia = 5, ib = 5;
#pragma unroll
    for (int k = 0; k < 6; k++) {
      unsigned va = (ia >= 0) ? (unsigned)A[ia] : 0u;
      unsigned vb = (ib >= 0) ? (unsigned)B[ib] : 0u;
      if (va >= vb) { dst[k] = va; ia--; }
      else          { dst[k] = vb; ib--; }
    }
  }
}

// --- screen: threshold 1536 packed candidates/row at 44th-largest ----------
__global__ __launch_bounds__(256) void k_screen(const unsigned* __restrict__ cand6,
                                                int* __restrict__ cntg,
                                                int* __restrict__ candg) {
  __shared__ int hist[512];
  __shared__ int hist2[128];
  __shared__ int sb_bstar, sb_chi, sb_cnt;
  __shared__ unsigned sb_tau;
  __shared__ int cand[CANDCAP];

  int tid = threadIdx.x, lane = tid & 63;
  int row = blockIdx.x;
  const unsigned* src = cand6 + (size_t)row * 1536 + tid * 6;
  unsigned pc0 = src[0], pc1 = src[1], pc2 = src[2],
           pc3 = src[3], pc4 = src[4], pc5 = src[5];

  hist[tid] = 0; hist[tid + 256] = 0;
  if (tid < 128) hist2[tid] = 0;
  if (tid == 0) sb_cnt = 0;
  __syncthreads();

  atomicAdd(&hist[pc0 >> 23], 1);
  atomicAdd(&hist[pc1 >> 23], 1);
  atomicAdd(&hist[pc2 >> 23], 1);
  atomicAdd(&hist[pc3 >> 23], 1);
  atomicAdd(&hist[pc4 >> 23], 1);
  atomicAdd(&hist[pc5 >> 23], 1);
  __syncthreads();

  // level-1: b* = max bin with suffix-count >= RTHRESH
  if (tid < 64) {
    int b = lane * 8;
    int h0 = hist[b], h1 = hist[b+1], h2 = hist[b+2], h3 = hist[b+3];
    int h4 = hist[b+4], h5 = hist[b+5], h6 = hist[b+6], h7 = hist[b+7];
    int s7 = h7, s6 = h6 + s7, s5 = h5 + s6, s4 = h4 + s5;
    int s3 = h3 + s4, s2 = h2 + s3, s1 = h1 + s2, s0 = h0 + s1;
    int tot = s0, acc = tot;
#pragma unroll
    for (int off = 1; off <= 32; off <<= 1) {
      int t = __shfl_down(acc, off);
      if (lane + off < 64) acc += t;
    }
    int excl = acc - tot;
    int best = -1, bs = 0, hb = 0;
    if (excl + s0 >= RTHRESH) { best = b + 0; bs = excl + s0; hb = h0; }
    if (excl + s1 >= RTHRESH) { best = b + 1; bs = excl + s1; hb = h1; }
    if (excl + s2 >= RTHRESH) { best = b + 2; bs = excl + s2; hb = h2; }
    if (excl + s3 >= RTHRESH) { best = b + 3; bs = excl + s3; hb = h3; }
    if (excl + s4 >= RTHRESH) { best = b + 4; bs = excl + s4; hb = h4; }
    if (excl + s5 >= RTHRESH) { best = b + 5; bs = excl + s5; hb = h5; }
    if (excl + s6 >= RTHRESH) { best = b + 6; bs = excl + s6; hb = h6; }
    if (excl + s7 >= RTHRESH) { best = b + 7; bs = excl + s7; hb = h7; }
#pragma unroll
    for (int off = 32; off > 0; off >>= 1) {
      int ob = __shfl_down(best, off), obs = __shfl_down(bs, off), ohb = __shfl_down(hb, off);
      if (lane + off < 64 && ob > best) { best = ob; bs = obs; hb = ohb; }
    }
    if (lane == 0) { sb_bstar = best; sb_chi = bs - hb; }
  }
  __syncthreads();
  int bstar = sb_bstar, chi = sb_chi;

  if ((int)(pc0 >> 23) == bstar) atomicAdd(&hist2[(pc0 >> 16) & 127], 1);
  if ((int)(pc1 >> 23) == bstar) atomicAdd(&hist2[(pc1 >> 16) & 127], 1);
  if ((int)(pc2 >> 23) == bstar) atomicAdd(&hist2[(pc2 >> 16) & 127], 1);
  if ((int)(pc3 >> 23) == bstar) atomicAdd(&hist2[(pc3 >> 16) & 127], 1);
  if ((int)(pc4 >> 23) == bstar) atomicAdd(&hist2[(pc4 >> 16) & 127], 1);
  if ((int)(pc5 >> 23) == bstar) atomicAdd(&hist2[(pc5 >> 16) & 127], 1);
  __syncthreads();

  // level-2: s* within bin b*
  if (tid < 64) {
    int g0 = hist2[lane * 2], g1 = hist2[lane * 2 + 1];
    int s1 = g1, s0 = g0 + g1;
    int tot = s0, acc = tot;
#pragma unroll
    for (int off = 1; off <= 32; off <<= 1) {
      int t = __shfl_down(acc, off);
      if (lane + off < 64) acc += t;
    }
    int excl = acc - tot;
    int best = -1;
    if (chi + excl + s0 >= RTHRESH) best = lane * 2;
    if (chi + excl + s1 >= RTHRESH) best = lane * 2 + 1;
#pragma unroll
    for (int off = 32; off > 0; off >>= 1) {
      int ob = __shfl_down(best, off);
      if (lane + off < 64 && ob > best) best = ob;
    }
    if (lane == 0) sb_tau = ((unsigned)((bstar << 7) | best)) << 16;
  }
  __syncthreads();

  unsigned tau = sb_tau;
#define EMIT(PC)                                                   \
  if ((PC) >= tau) {                                               \
    int pos = atomicAdd(&sb_cnt, 1);                               \
    if (pos < CANDCAP) cand[pos] = tid * 128 + (int)((PC) & 127u); \
  }
  EMIT(pc0) EMIT(pc1) EMIT(pc2) EMIT(pc3) EMIT(pc4) EMIT(pc5)
#undef EMIT
  __syncthreads();

  int cnt = sb_cnt < CANDCAP ? sb_cnt : CANDCAP;
  if (tid == 0) cntg[row] = cnt;
  if (tid < CANDCAP) candg[(size_t)row * CANDCAP + tid] = (tid < cnt) ? cand[tid] : 0;
}

// ------- refine candidates exact fp32, top-32, decode, de-normalize --------
// FROZEN byte-exact (summation order is selection-critical vs np reference)
__global__ __launch_bounds__(256) void k_sel(const float* __restrict__ x,
                                             const float* __restrict__ pre_bias,
                                             const float* __restrict__ latent_bias,
                                             const float* __restrict__ enc,
                                             const unsigned short* __restrict__ dect,
                                             const int* __restrict__ cntg,
                                             const int* __restrict__ candg,
                                             const float* __restrict__ meanA,
                                             const float* __restrict__ stdA,
                                             float* __restrict__ out) {
  __shared__ __align__(16) float xn[DIM];
  __shared__ float exactv[128];
  __shared__ int self_[128];
  __shared__ float hv[TOPK];
  __shared__ int hf[TOPK];

  int row = blockIdx.x, tid = threadIdx.x, lane = tid & 63;
  float m = meanA[row], s = stdA[row], inv = 1.0f / s;
  const float* xr = x + (size_t)row * DIM;
  for (int i = tid; i < DIM; i += 256)
    xn[i] = (xr[i] - m) * inv - pre_bias[i];
  int cnt = cntg[row];  // in [RTHRESH, CANDCAP]
  if (tid < 128) {
    self_[tid] = (tid < cnt) ? candg[(size_t)row * CANDCAP + tid] : 0x7FFFFFF;
    exactv[tid] = -3.0e38f;
  }
  __syncthreads();

#pragma unroll
  for (int pass = 0; pass < 2; pass++) {
    int g = pass * 64 + (tid >> 2), t4 = tid & 3;
    if (g < cnt) {
      int f = self_[g];
      const float4* xp = (const float4*)xn;
      const float4* wp = (const float4*)(enc + (size_t)f * DIM);
      float acc = 0.f;
      for (int i = t4; i < DIM / 4; i += 4) {
        float4 a = xp[i], b = wp[i];
        acc = fmaf(a.x, b.x, acc);
        acc = fmaf(a.y, b.y, acc);
        acc = fmaf(a.z, b.z, acc);
        acc = fmaf(a.w, b.w, acc);
      }
      acc += __shfl_xor(acc, 1);
      acc += __shfl_xor(acc, 2);
      if (t4 == 0) exactv[g] = acc + latent_bias[f];
    }
  }
  __syncthreads();

  if (tid < 64) {
    float v0 = exactv[lane];      int f0 = self_[lane];
    float v1 = exactv[lane + 64]; int f1 = self_[lane + 64];
    for (int r = 0; r < TOPK; r++) {
      float bv = v0; int bf = f0;
      if (v1 > bv || (v1 == bv && f1 < bf)) { bv = v1; bf = f1; }
#pragma unroll
      for (int off = 32; off > 0; off >>= 1) {
        float ov = __shfl_down(bv, off);
        int of = __shfl_down(bf, off);
        if (lane + off < 64 && (ov > bv || (ov == bv && of < bf))) { bv = ov; bf = of; }
      }
      bv = __shfl(bv, 0);
      bf = __shfl(bf, 0);
      if (lane == 0) { hv[r] = bv > 0.f ? bv : 0.f; hf[r] = bf; }
      if (f0 == bf) v0 = -3.0e38f;
      if (f1 == bf) v1 = -3.0e38f;
    }
  }
  __syncthreads();

  float* orow = out + (size_t)row * DIM;
#pragma unroll
  for (int t = 0; t < 3; t++) {
    int c = tid + t * 256;
    float acc = pre_bias[c];
    for (int j = 0; j < TOPK; j++)
      acc = fmaf(hv[j], bf2f(dect[(size_t)hf[j] * DIM + c]), acc);
    orow[c] = acc * s + m;
  }
}

extern "C" void kernel_launch(void* const* d_in, const int* in_sizes, int n_in,
                              void* d_out, int out_size, void* d_ws, size_t ws_size,
                              hipStream_t stream) {
  const float* x   = (const float*)d_in[0];
  const float* pb  = (const float*)d_in[1];
  const float* lb  = (const float*)d_in[2];
  const float* enc = (const float*)d_in[3];
  const float* dec = (const float*)d_in[4];
  float* out = (float*)d_out;

  // fixed workspace layout (bytes)
  const size_t off_xh   = 0;            // 12,582,912
  const size_t off_ench = 12582912;     // 50,331,648
  const size_t off_dect = 62914560;     // 50,331,648 (bf16)
  const size_t off_mean = 113246208;    // 32,768
  const size_t off_std  = 113278976;    // 32,768
  const size_t off_cnt  = 113311744;    // 32,768
  const size_t off_cand = 113344512;    // 2,359,296
  const size_t off_c6   = 115703808;    // 8192*256*6*4 = 50,331,648
  if (ws_size < 166035456) return;      // cannot run

  char* ws = (char*)d_ws;
  unsigned short* xh   = (unsigned short*)(ws + off_xh);
  unsigned short* ench = (unsigned short*)(ws + off_ench);
  unsigned short* dect = (unsigned short*)(ws + off_dect);
  float* meanA = (float*)(ws + off_mean);
  float* stdA  = (float*)(ws + off_std);
  int*   cntg  = (int*)(ws + off_cnt);
  int*   candg = (int*)(ws + off_cand);
  unsigned* cand6 = (unsigned*)(ws + off_c6);

  hipLaunchKernelGGL(k_ln, dim3(N_ROWS), dim3(256), 0, stream, x, pb, xh, meanA, stdA);
  hipLaunchKernelGGL(k_cv, dim3((NF * DIM / 4 + 255) / 256), dim3(256), 0, stream,
                     enc, ench, NF * DIM / 4);
  hipLaunchKernelGGL(k_tr, dim3(NF / 32, DIM / 32), dim3(256), 0, stream, dec, dect);

  hipLaunchKernelGGL(k_gemm, dim3(NF / 128, N_ROWS / 256), dim3(512), 0, stream,
                     xh, ench, lb, cand6);
  hipLaunchKernelGGL(k_screen, dim3(N_ROWS), dim3(256), 0, stream, cand6, cntg, candg);

  hipLaunchKernelGGL(k_sel, dim3(N_ROWS), dim3(256), 0, stream,
                     x, pb, lb, enc, dect, cntg, candg, meanA, stdA, out);
}

// Round 9
// 1073.476 us; speedup vs baseline: 2.7304x; 1.0259x over previous
//
#include <hip/hip_runtime.h>
#include <hip/hip_bf16.h>
#include <stdint.h>

#define N_ROWS 8192
#define DIM 768
#define NF 32768
#define TOPK 32
#define CANDCAP 72
#define RTHRESH 44

typedef __attribute__((ext_vector_type(8))) short bf16x8;
typedef __attribute__((ext_vector_type(8))) short short8;
typedef __attribute__((ext_vector_type(4))) float f32x4;

__device__ inline void async_ld16(const void* g, void* l) {
  __builtin_amdgcn_global_load_lds(
      (const __attribute__((address_space(1))) unsigned int*)g,
      (__attribute__((address_space(3))) unsigned int*)l, 16, 0, 0);
}

__device__ inline unsigned short f2bf(float f) {
  union { float f; unsigned u; } c; c.f = f;
  unsigned r = c.u + 0x7FFFu + ((c.u >> 16) & 1u);  // RNE
  return (unsigned short)(r >> 16);
}

__device__ inline float bf2f(unsigned short u) {
  union { unsigned u; float f; } c; c.u = ((unsigned)u) << 16;
  return c.f;
}

// barrier that is ALSO a compiler-level memory fence
__device__ inline void block_barrier_fenced() {
  __builtin_amdgcn_s_barrier();
  asm volatile("" ::: "memory");
  __builtin_amdgcn_sched_barrier(0);
}

// ---------------- LayerNorm: mean/std per row, x_norm -> bf16 ----------------
__global__ __launch_bounds__(256) void k_ln(const float* __restrict__ x,
                                            const float* __restrict__ pre_bias,
                                            unsigned short* __restrict__ xh,
                                            float* __restrict__ meanA,
                                            float* __restrict__ stdA) {
  int row = blockIdx.x;
  int tid = threadIdx.x;
  int lane = tid & 63, wv = tid >> 6;
  const float* xr = x + (size_t)row * DIM;
  float a0 = xr[tid], a1 = xr[tid + 256], a2 = xr[tid + 512];
  __shared__ float red[8];
  float s = a0 + a1 + a2;
  for (int off = 32; off > 0; off >>= 1) s += __shfl_down(s, off);
  if (lane == 0) red[wv] = s;
  __syncthreads();
  float mean;
  if (tid == 0) { mean = (red[0] + red[1] + red[2] + red[3]) / (float)DIM; red[4] = mean; }
  __syncthreads();
  mean = red[4];
  float d0 = a0 - mean, d1 = a1 - mean, d2 = a2 - mean;
  float ss = d0 * d0 + d1 * d1 + d2 * d2;
  for (int off = 32; off > 0; off >>= 1) ss += __shfl_down(ss, off);
  if (lane == 0) red[wv] = ss;
  __syncthreads();
  float stdv;
  if (tid == 0) {
    float var = (red[0] + red[1] + red[2] + red[3]) / (float)DIM;
    stdv = sqrtf(var + 1e-5f);
    red[5] = stdv;
    meanA[row] = mean;
    stdA[row] = stdv;
  }
  __syncthreads();
  stdv = red[5];
  float inv = 1.0f / stdv;
  unsigned short* xo = xh + (size_t)row * DIM;
  xo[tid]       = f2bf(d0 * inv - pre_bias[tid]);
  xo[tid + 256] = f2bf(d1 * inv - pre_bias[tid + 256]);
  xo[tid + 512] = f2bf(d2 * inv - pre_bias[tid + 512]);
}

// ---------------- enc_w fp32 -> bf16 ----------------
__global__ __launch_bounds__(256) void k_cv(const float* __restrict__ w,
                                            unsigned short* __restrict__ o, int n4) {
  int i = blockIdx.x * 256 + threadIdx.x;
  if (i >= n4) return;
  float4 v = ((const float4*)w)[i];
  ushort4 r;
  r.x = f2bf(v.x); r.y = f2bf(v.y); r.z = f2bf(v.z); r.w = f2bf(v.w);
  ((ushort4*)o)[i] = r;
}

// -------- transpose dec_w (768 x 32768) -> dect (32768 x 768) bf16 --------
__global__ __launch_bounds__(256) void k_tr(const float* __restrict__ dec,
                                            unsigned short* __restrict__ dect) {
  __shared__ float t[32][33];
  int tx = threadIdx.x & 31, ty = threadIdx.x >> 5;  // 32 x 8
  int fb = blockIdx.x * 32, cb = blockIdx.y * 32;
  for (int i = 0; i < 4; i++) {
    int r = ty + i * 8;
    t[r][tx] = dec[(size_t)(cb + r) * NF + fb + tx];
  }
  __syncthreads();
  for (int i = 0; i < 4; i++) {
    int r = ty + i * 8;
    dect[(size_t)(fb + r) * DIM + cb + tx] = f2bf(t[tx][r]);
  }
}

// ---- 256x256 bf16 MFMA GEMM, BK=64, 2-buffer ping-pong, counted vmcnt(8) --
// ---- fused per-(row, 128-col-slice) top-6 candidate epilogue --------------
// cand6[row][slice(256)][0..5] = (orderable_fp32_key & 0xFFFFFF00) | col7
// LDS (STATIC 147456): ring sA[2]x32K @0, sB[2]x32K @65536; epilogue reuse:
//   sC[256][129] f32 @0 (132096 B) + m6[512][6] int (12288 B)
__global__ __launch_bounds__(512, 2) void k_gemm(const unsigned short* __restrict__ xh,
                                                 const unsigned short* __restrict__ ench,
                                                 const float* __restrict__ latent_bias,
                                                 unsigned* __restrict__ cand6) {
  __shared__ __align__(16) char smem[147456];
  int tid = threadIdx.x;
  int lane = tid & 63;
  int w = tid >> 6;
  int wr = w >> 2, wc = w & 3;      // 2 M-waves x 4 N-waves; wave out = 128x64
  int bx = blockIdx.x;              // N tile (feature / 256)
  int by = blockIdx.y;              // M tile (row / 256)
  const int fr = lane & 15, hi = lane >> 4;

  const char* Ab = (const char*)(xh + (size_t)by * 256 * DIM);
  const char* Bb = (const char*)(ench + (size_t)bx * 256 * DIM);

  // staging geometry (proven): L = i*8192 + tid*16 covers 32 KB (256 rows x
  // 128 B); source col pre-swizzled so swizzled ds_read sees row-major data
  int rA[4], cA[4];
#pragma unroll
  for (int i = 0; i < 4; i++) {
    int L = i * 8192 + tid * 16;
    int r = L >> 7;
    rA[i] = r;
    cA[i] = (L & 127) ^ ((r & 7) << 4);
  }

  f32x4 acc[8][4];
#pragma unroll
  for (int m = 0; m < 8; m++)
#pragma unroll
    for (int n = 0; n < 4; n++) {
      f32x4 z = {0.f, 0.f, 0.f, 0.f};
      acc[m][n] = z;
    }

#define STAGE(kt, b)                                                          \
  do {                                                                        \
    char* dA = smem + (b) * 32768;                                            \
    char* dB = smem + 65536 + (b) * 32768;                                    \
    _Pragma("unroll") for (int i = 0; i < 4; i++)                             \
        async_ld16(Ab + (size_t)rA[i] * (DIM * 2) + (kt) * 128 + cA[i],       \
                   dA + i * 8192 + tid * 16);                                 \
    _Pragma("unroll") for (int i = 0; i < 4; i++)                             \
        async_ld16(Bb + (size_t)rA[i] * (DIM * 2) + (kt) * 128 + cA[i],       \
                   dB + i * 8192 + tid * 16);                                 \
  } while (0)

  STAGE(0, 0);  // 8 loads in flight

  for (int kt = 0; kt < 12; kt++) {
    int b = kt & 1;
    // issue next stage FIRST, then counted wait: after STAGE(kt+1) the 8
    // newest outstanding are kt+1's, so vmcnt(8) => STAGE(kt) has landed.
    if (kt + 1 < 12) {
      STAGE(kt + 1, (kt + 1) & 1);
      asm volatile("s_waitcnt vmcnt(8)" ::: "memory");
    } else {
      asm volatile("s_waitcnt vmcnt(0)" ::: "memory");
    }
    block_barrier_fenced();  // all waves' STAGE(kt) visible

    const char* pA = smem + b * 32768;
    const char* pB = smem + 65536 + b * 32768;
#pragma unroll
    for (int kh = 0; kh < 2; kh++) {
      bf16x8 af[8], bv[4];
      int cbb = kh * 64 + hi * 16;
#pragma unroll
      for (int m = 0; m < 8; m++) {
        int row = wr * 128 + m * 16 + fr;
        af[m] = *(const bf16x8*)(pA + row * 128 + (cbb ^ ((row & 7) << 4)));
      }
#pragma unroll
      for (int n = 0; n < 4; n++) {
        int row = wc * 64 + n * 16 + fr;
        bv[n] = *(const bf16x8*)(pB + row * 128 + (cbb ^ ((row & 7) << 4)));
      }
      __builtin_amdgcn_s_setprio(1);
#pragma unroll
      for (int m = 0; m < 8; m++)
#pragma unroll
        for (int n = 0; n < 4; n++)
          acc[m][n] = __builtin_amdgcn_mfma_f32_16x16x32_bf16(af[m], bv[n], acc[m][n], 0, 0, 0);
      __builtin_amdgcn_s_setprio(0);
    }
    // reads of buf b done; next iter overwrites b^... STAGE(kt+2) targets b,
    // issued only after every wave passes this barrier.
    block_barrier_fenced();
  }
#undef STAGE

  // ---- fused epilogue: two 128-col half-passes ----------------------------
  float* sC = (float*)smem;                 // [256][129]
  int* m6 = (int*)(smem + 132096);          // [512][6]
#pragma unroll
  for (int p = 0; p < 2; p++) {
    if ((wc >> 1) == p) {
#pragma unroll
      for (int n = 0; n < 4; n++) {
        int lcol = (wc & 1) * 64 + n * 16 + fr;
        float lbv = latent_bias[bx * 256 + p * 128 + lcol];
#pragma unroll
        for (int m = 0; m < 8; m++) {
          int lrow = wr * 128 + m * 16 + hi * 4;
#pragma unroll
          for (int j = 0; j < 4; j++)
            sC[(lrow + j) * 129 + lcol] = acc[m][n][j] + lbv;
        }
      }
    }
    __syncthreads();
    {
      int r = tid >> 1, half = tid & 1;
      const float* cr = sC + r * 129 + half * 64;
      unsigned c0 = 0, c1 = 0, c2 = 0, c3 = 0, c4 = 0, c5 = 0;
      for (int c = 0; c < 64; c++) {
        union { float f; unsigned u; } cv; cv.f = cr[c];
        unsigned key = ((int)cv.u < 0) ? ~cv.u : (cv.u | 0x80000000u);
        unsigned pk = (key & 0xFFFFFF00u) | (unsigned)(half * 64 + c);
        if (pk > c0) {
          bool b1 = pk > c1, b2 = pk > c2, b3 = pk > c3, b4 = pk > c4, b5 = pk > c5;
          c0 = b1 ? c1 : pk;
          c1 = b1 ? (b2 ? c2 : pk) : c1;
          c2 = b2 ? (b3 ? c3 : pk) : c2;
          c3 = b3 ? (b4 ? c4 : pk) : c3;
          c4 = b4 ? (b5 ? c5 : pk) : c4;
          c5 = b5 ? pk : c5;
        }
      }
      int* mp = m6 + tid * 6;
      mp[0] = (int)c0; mp[1] = (int)c1; mp[2] = (int)c2;
      mp[3] = (int)c3; mp[4] = (int)c4; mp[5] = (int)c5;
    }
    __syncthreads();
    if (tid < 256) {
      const int* A = m6 + (2 * tid) * 6;
      const int* B = m6 + (2 * tid + 1) * 6;
      unsigned* dst = cand6 + ((size_t)(by * 256 + tid) * 256 + (bx * 2 + p)) * 6;
      int ia = 5, ib = 5;
#pragma unroll
      for (int k = 0; k < 6; k++) {
        unsigned va = (ia >= 0) ? (unsigned)A[ia] : 0u;
        unsigned vb = (ib >= 0) ? (unsigned)B[ib] : 0u;
        if (va >= vb) { dst[k] = va; ia--; }
        else          { dst[k] = vb; ib--; }
      }
    }
    __syncthreads();
  }
}

// --- screen: threshold 1536 packed candidates/row at 44th-largest ----------
__global__ __launch_bounds__(256) void k_screen(const unsigned* __restrict__ cand6,
                                                int* __restrict__ cntg,
                                                int* __restrict__ candg) {
  __shared__ int hist[512];
  __shared__ int hist2[128];
  __shared__ int sb_bstar, sb_chi, sb_cnt;
  __shared__ unsigned sb_tau;
  __shared__ int cand[CANDCAP];

  int tid = threadIdx.x, lane = tid & 63;
  int row = blockIdx.x;
  const unsigned* src = cand6 + (size_t)row * 1536 + tid * 6;
  unsigned pc0 = src[0], pc1 = src[1], pc2 = src[2],
           pc3 = src[3], pc4 = src[4], pc5 = src[5];

  hist[tid] = 0; hist[tid + 256] = 0;
  if (tid < 128) hist2[tid] = 0;
  if (tid == 0) sb_cnt = 0;
  __syncthreads();

  atomicAdd(&hist[pc0 >> 23], 1);
  atomicAdd(&hist[pc1 >> 23], 1);
  atomicAdd(&hist[pc2 >> 23], 1);
  atomicAdd(&hist[pc3 >> 23], 1);
  atomicAdd(&hist[pc4 >> 23], 1);
  atomicAdd(&hist[pc5 >> 23], 1);
  __syncthreads();

  if (tid < 64) {
    int b = lane * 8;
    int h0 = hist[b], h1 = hist[b+1], h2 = hist[b+2], h3 = hist[b+3];
    int h4 = hist[b+4], h5 = hist[b+5], h6 = hist[b+6], h7 = hist[b+7];
    int s7 = h7, s6 = h6 + s7, s5 = h5 + s6, s4 = h4 + s5;
    int s3 = h3 + s4, s2 = h2 + s3, s1 = h1 + s2, s0 = h0 + s1;
    int tot = s0, acc = tot;
#pragma unroll
    for (int off = 1; off <= 32; off <<= 1) {
      int t = __shfl_down(acc, off);
      if (lane + off < 64) acc += t;
    }
    int excl = acc - tot;
    int best = -1, bs = 0, hb = 0;
    if (excl + s0 >= RTHRESH) { best = b + 0; bs = excl + s0; hb = h0; }
    if (excl + s1 >= RTHRESH) { best = b + 1; bs = excl + s1; hb = h1; }
    if (excl + s2 >= RTHRESH) { best = b + 2; bs = excl + s2; hb = h2; }
    if (excl + s3 >= RTHRESH) { best = b + 3; bs = excl + s3; hb = h3; }
    if (excl + s4 >= RTHRESH) { best = b + 4; bs = excl + s4; hb = h4; }
    if (excl + s5 >= RTHRESH) { best = b + 5; bs = excl + s5; hb = h5; }
    if (excl + s6 >= RTHRESH) { best = b + 6; bs = excl + s6; hb = h6; }
    if (excl + s7 >= RTHRESH) { best = b + 7; bs = excl + s7; hb = h7; }
#pragma unroll
    for (int off = 32; off > 0; off >>= 1) {
      int ob = __shfl_down(best, off), obs = __shfl_down(bs, off), ohb = __shfl_down(hb, off);
      if (lane + off < 64 && ob > best) { best = ob; bs = obs; hb = ohb; }
    }
    if (lane == 0) { sb_bstar = best; sb_chi = bs - hb; }
  }
  __syncthreads();
  int bstar = sb_bstar, chi = sb_chi;

  if ((int)(pc0 >> 23) == bstar) atomicAdd(&hist2[(pc0 >> 16) & 127], 1);
  if ((int)(pc1 >> 23) == bstar) atomicAdd(&hist2[(pc1 >> 16) & 127], 1);
  if ((int)(pc2 >> 23) == bstar) atomicAdd(&hist2[(pc2 >> 16) & 127], 1);
  if ((int)(pc3 >> 23) == bstar) atomicAdd(&hist2[(pc3 >> 16) & 127], 1);
  if ((int)(pc4 >> 23) == bstar) atomicAdd(&hist2[(pc4 >> 16) & 127], 1);
  if ((int)(pc5 >> 23) == bstar) atomicAdd(&hist2[(pc5 >> 16) & 127], 1);
  __syncthreads();

  if (tid < 64) {
    int g0 = hist2[lane * 2], g1 = hist2[lane * 2 + 1];
    int s1 = g1, s0 = g0 + g1;
    int tot = s0, acc = tot;
#pragma unroll
    for (int off = 1; off <= 32; off <<= 1) {
      int t = __shfl_down(acc, off);
      if (lane + off < 64) acc += t;
    }
    int excl = acc - tot;
    int best = -1;
    if (chi + excl + s0 >= RTHRESH) best = lane * 2;
    if (chi + excl + s1 >= RTHRESH) best = lane * 2 + 1;
#pragma unroll
    for (int off = 32; off > 0; off >>= 1) {
      int ob = __shfl_down(best, off);
      if (lane + off < 64 && ob > best) best = ob;
    }
    if (lane == 0) sb_tau = ((unsigned)((bstar << 7) | best)) << 16;
  }
  __syncthreads();

  unsigned tau = sb_tau;
#define EMIT(PC)                                                   \
  if ((PC) >= tau) {                                               \
    int pos = atomicAdd(&sb_cnt, 1);                               \
    if (pos < CANDCAP) cand[pos] = tid * 128 + (int)((PC) & 127u); \
  }
  EMIT(pc0) EMIT(pc1) EMIT(pc2) EMIT(pc3) EMIT(pc4) EMIT(pc5)
#undef EMIT
  __syncthreads();

  int cnt = sb_cnt < CANDCAP ? sb_cnt : CANDCAP;
  if (tid == 0) cntg[row] = cnt;
  if (tid < CANDCAP) candg[(size_t)row * CANDCAP + tid] = (tid < cnt) ? cand[tid] : 0;
}

// ------- refine candidates exact fp32, top-32, decode, de-normalize --------
// FROZEN byte-exact (summation order is selection-critical vs np reference)
__global__ __launch_bounds__(256) void k_sel(const float* __restrict__ x,
                                             const float* __restrict__ pre_bias,
                                             const float* __restrict__ latent_bias,
                                             const float* __restrict__ enc,
                                             const unsigned short* __restrict__ dect,
                                             const int* __restrict__ cntg,
                                             const int* __restrict__ candg,
                                             const float* __restrict__ meanA,
                                             const float* __restrict__ stdA,
                                             float* __restrict__ out) {
  __shared__ __align__(16) float xn[DIM];
  __shared__ float exactv[128];
  __shared__ int self_[128];
  __shared__ float hv[TOPK];
  __shared__ int hf[TOPK];

  int row = blockIdx.x, tid = threadIdx.x, lane = tid & 63;
  float m = meanA[row], s = stdA[row], inv = 1.0f / s;
  const float* xr = x + (size_t)row * DIM;
  for (int i = tid; i < DIM; i += 256)
    xn[i] = (xr[i] - m) * inv - pre_bias[i];
  int cnt = cntg[row];  // in [RTHRESH, CANDCAP]
  if (tid < 128) {
    self_[tid] = (tid < cnt) ? candg[(size_t)row * CANDCAP + tid] : 0x7FFFFFF;
    exactv[tid] = -3.0e38f;
  }
  __syncthreads();

#pragma unroll
  for (int pass = 0; pass < 2; pass++) {
    int g = pass * 64 + (tid >> 2), t4 = tid & 3;
    if (g < cnt) {
      int f = self_[g];
      const float4* xp = (const float4*)xn;
      const float4* wp = (const float4*)(enc + (size_t)f * DIM);
      float acc = 0.f;
      for (int i = t4; i < DIM / 4; i += 4) {
        float4 a = xp[i], b = wp[i];
        acc = fmaf(a.x, b.x, acc);
        acc = fmaf(a.y, b.y, acc);
        acc = fmaf(a.z, b.z, acc);
        acc = fmaf(a.w, b.w, acc);
      }
      acc += __shfl_xor(acc, 1);
      acc += __shfl_xor(acc, 2);
      if (t4 == 0) exactv[g] = acc + latent_bias[f];
    }
  }
  __syncthreads();

  if (tid < 64) {
    float v0 = exactv[lane];      int f0 = self_[lane];
    float v1 = exactv[lane + 64]; int f1 = self_[lane + 64];
    for (int r = 0; r < TOPK; r++) {
      float bv = v0; int bf = f0;
      if (v1 > bv || (v1 == bv && f1 < bf)) { bv = v1; bf = f1; }
#pragma unroll
      for (int off = 32; off > 0; off >>= 1) {
        float ov = __shfl_down(bv, off);
        int of = __shfl_down(bf, off);
        if (lane + off < 64 && (ov > bv || (ov == bv && of < bf))) { bv = ov; bf = of; }
      }
      bv = __shfl(bv, 0);
      bf = __shfl(bf, 0);
      if (lane == 0) { hv[r] = bv > 0.f ? bv : 0.f; hf[r] = bf; }
      if (f0 == bf) v0 = -3.0e38f;
      if (f1 == bf) v1 = -3.0e38f;
    }
  }
  __syncthreads();

  float* orow = out + (size_t)row * DIM;
#pragma unroll
  for (int t = 0; t < 3; t++) {
    int c = tid + t * 256;
    float acc = pre_bias[c];
    for (int j = 0; j < TOPK; j++)
      acc = fmaf(hv[j], bf2f(dect[(size_t)hf[j] * DIM + c]), acc);
    orow[c] = acc * s + m;
  }
}

extern "C" void kernel_launch(void* const* d_in, const int* in_sizes, int n_in,
                              void* d_out, int out_size, void* d_ws, size_t ws_size,
                              hipStream_t stream) {
  const float* x   = (const float*)d_in[0];
  const float* pb  = (const float*)d_in[1];
  const float* lb  = (const float*)d_in[2];
  const float* enc = (const float*)d_in[3];
  const float* dec = (const float*)d_in[4];
  float* out = (float*)d_out;

  // fixed workspace layout (bytes)
  const size_t off_xh   = 0;            // 12,582,912
  const size_t off_ench = 12582912;     // 50,331,648
  const size_t off_dect = 62914560;     // 50,331,648 (bf16)
  const size_t off_mean = 113246208;    // 32,768
  const size_t off_std  = 113278976;    // 32,768
  const size_t off_cnt  = 113311744;    // 32,768
  const size_t off_cand = 113344512;    // 2,359,296
  const size_t off_c6   = 115703808;    // 8192*256*6*4 = 50,331,648
  if (ws_size < 166035456) return;      // cannot run

  char* ws = (char*)d_ws;
  unsigned short* xh   = (unsigned short*)(ws + off_xh);
  unsigned short* ench = (unsigned short*)(ws + off_ench);
  unsigned short* dect = (unsigned short*)(ws + off_dect);
  float* meanA = (float*)(ws + off_mean);
  float* stdA  = (float*)(ws + off_std);
  int*   cntg  = (int*)(ws + off_cnt);
  int*   candg = (int*)(ws + off_cand);
  unsigned* cand6 = (unsigned*)(ws + off_c6);

  hipLaunchKernelGGL(k_ln, dim3(N_ROWS), dim3(256), 0, stream, x, pb, xh, meanA, stdA);
  hipLaunchKernelGGL(k_cv, dim3((NF * DIM / 4 + 255) / 256), dim3(256), 0, stream,
                     enc, ench, NF * DIM / 4);
  hipLaunchKernelGGL(k_tr, dim3(NF / 32, DIM / 32), dim3(256), 0, stream, dec, dect);

  hipLaunchKernelGGL(k_gemm, dim3(NF / 256, N_ROWS / 256), dim3(512), 0, stream,
                     xh, ench, lb, cand6);
  hipLaunchKernelGGL(k_screen, dim3(N_ROWS), dim3(256), 0, stream, cand6, cntg, candg);

  hipLaunchKernelGGL(k_sel, dim3(N_ROWS), dim3(256), 0, stream,
                     x, pb, lb, enc, dect, cntg, candg, meanA, stdA, out);
}